// Round 6
// baseline (629.988 us; speedup 1.0000x reference)
//
#include <hip/hip_runtime.h>
#include <hip/hip_bf16.h>
#include <math.h>

#define EPS_LN 1e-5f

typedef __attribute__((ext_vector_type(8))) short bf16x8;
typedef __attribute__((ext_vector_type(4))) float f32x4;
typedef __attribute__((ext_vector_type(2))) unsigned short u16x2;
typedef __attribute__((ext_vector_type(4))) unsigned int u32x4;

__device__ __forceinline__ unsigned short f2bf(float f) {
    __hip_bfloat16 h = __float2bfloat16(f);
    return *reinterpret_cast<unsigned short*>(&h);
}
__device__ __forceinline__ float bf2f(unsigned short u) {
    return __uint_as_float(((unsigned)u) << 16);
}
// monotone 16-bit key of a bf16 pattern; 0 is below all real values
__device__ __forceinline__ unsigned short ok16(float f) {
    unsigned short t = f2bf(f);
    unsigned short mask = (unsigned short)(((short)t) >> 15);
    return (unsigned short)(t ^ (unsigned short)(mask | 0x8000u));
}
// decode segord entry (key16<<16; 0 == empty -> 0.0)
__device__ __forceinline__ float decseg(unsigned o) {
    if (o == 0u) return 0.f;
    unsigned k = o >> 16;
    unsigned h = (k & 0x8000u) ? (k & 0x7FFFu) : (~k & 0xFFFFu);
    return bf2f((unsigned short)h);
}

// ---------------------------------------------------------------------------
// K0: prep — pack params once per call.
// ---------------------------------------------------------------------------
__global__ __launch_bounds__(256) void prep_kernel(
    const float* __restrict__ W1, const float* __restrict__ b1,
    const float* __restrict__ g1, const float* __restrict__ be1,
    const float* __restrict__ W2,
    const float* __restrict__ W3, const float* __restrict__ W4,
    float* __restrict__ pW1e, float* __restrict__ pGB, float* __restrict__ pSG,
    unsigned short* __restrict__ pW2t,
    unsigned short* __restrict__ W3th, unsigned short* __restrict__ W3tl,
    unsigned short* __restrict__ W4th, unsigned short* __restrict__ W4tl)
{
    const int tid = threadIdx.x;
    if (tid < 64) {
        pW1e[4 * tid + 0] = W1[tid];
        pW1e[4 * tid + 1] = W1[64 + tid];
        pW1e[4 * tid + 2] = W1[128 + tid];
        pW1e[4 * tid + 3] = b1[tid];
        pGB[2 * tid + 0] = g1[tid];
        pGB[2 * tid + 1] = be1[tid];
    }
    if (tid >= 64 && tid < 78) {
        const int t = tid - 64;
        auto wcomp = [&](int k, int i) -> float {
            return (i < 3) ? W1[i * 64 + k] : b1[k];
        };
        if (t < 4) {
            float s = 0.f;
            for (int k = 0; k < 64; k++) s += wcomp(k, t);
            pSG[t] = s;
        } else {
            const int pi[10] = {0,0,0,0,1,1,1,2,2,3};
            const int pj[10] = {0,1,2,3,1,2,3,2,3,3};
            int p = t - 4;
            float s = 0.f;
            for (int k = 0; k < 64; k++) s += wcomp(k, pi[p]) * wcomp(k, pj[p]);
            pSG[4 + p] = s;
        }
    }
    for (int i = tid; i < 4096; i += 256) {
        int k = i >> 6, n = i & 63;
        pW2t[n * 72 + k] = f2bf(W2[i]);
    }
    for (int i = tid; i < 64 * 8; i += 256) {
        int n = i >> 3, k = 64 + (i & 7);
        pW2t[n * 72 + k] = 0;
    }
    for (int i = tid; i < 8192; i += 256) {
        int k = i >> 7, n = i & 127;
        float w = W3[k * 128 + n];
        unsigned short h = f2bf(w);
        W3th[n * 64 + k] = h;
        W3tl[n * 64 + k] = f2bf(w - bf2f(h));
    }
    for (int i = tid; i < 16384; i += 256) {
        int k = i >> 7, n = i & 127;
        float w = W4[k * 128 + n];
        unsigned short h = f2bf(w);
        W4th[n * 128 + k] = h;
        W4tl[n * 128 + k] = f2bf(w - bf2f(h));
    }
}

// ---------------------------------------------------------------------------
// c1: node-level histogram via direct global atomics (64K addresses,
// ~32 adds/address, fire-and-forget, table L2-resident).
// ---------------------------------------------------------------------------
__global__ __launch_bounds__(256) void c1_count(const int* __restrict__ bidx,
                                                unsigned* __restrict__ nodeCount, int P) {
    const int p0 = blockIdx.x * 1024 + threadIdx.x * 4;
    if (p0 + 3 < P) {
        int4 n4 = *(const int4*)(bidx + p0);
        atomicAdd(&nodeCount[(unsigned)n4.x], 1u);
        atomicAdd(&nodeCount[(unsigned)n4.y], 1u);
        atomicAdd(&nodeCount[(unsigned)n4.z], 1u);
        atomicAdd(&nodeCount[(unsigned)n4.w], 1u);
    } else {
        for (int p = p0; p < P && p < p0 + 4; p++)
            atomicAdd(&nodeCount[(unsigned)bidx[p]], 1u);
    }
}

// ---------------------------------------------------------------------------
// c2: exclusive scan of nodeCount[N] -> offsets[N+1] and cursor[N].
// Single block, 1024 threads, CH elements each (re-reads L2-hot counts).
// ---------------------------------------------------------------------------
__global__ __launch_bounds__(1024) void c2_scan(const unsigned* __restrict__ nodeCount,
                                                unsigned* __restrict__ offsets,
                                                unsigned* __restrict__ cursor,
                                                int N, int P) {
    __shared__ unsigned wsum[16];
    const int t = threadIdx.x;
    const int CH = (N + 1023) >> 10;
    const int b0 = t * CH;

    unsigned s = 0;
    for (int i = 0; i < CH; i++) {
        const int idx = b0 + i;
        if (idx < N) s += nodeCount[idx];
    }
    unsigned v = s;
    const int lane = t & 63;
    for (int off = 1; off < 64; off <<= 1) {
        unsigned u = __shfl_up(v, off);
        if (lane >= off) v += u;
    }
    if (lane == 63) wsum[t >> 6] = v;
    __syncthreads();
    if (t == 0) {
        unsigned a = 0;
        for (int w = 0; w < 16; w++) { unsigned tmp = wsum[w]; wsum[w] = a; a += tmp; }
    }
    __syncthreads();
    unsigned run = wsum[t >> 6] + (v - s);
    for (int i = 0; i < CH; i++) {
        const int idx = b0 + i;
        if (idx < N) {
            offsets[idx] = run;
            cursor[idx]  = run;
            run += nodeCount[idx];
        }
    }
    if (t == 0) offsets[N] = (unsigned)P;
}

// ---------------------------------------------------------------------------
// c3: scatter (x,node) float4 into node-sorted xb via global cursor atomics.
// Within-node order nondeterministic — irrelevant for max pooling.
// ---------------------------------------------------------------------------
__global__ __launch_bounds__(256) void c3_scatter(const int* __restrict__ bidx,
                                                  const float* __restrict__ x,
                                                  unsigned* __restrict__ cursor,
                                                  float4* __restrict__ xb, int P) {
    const int tid = threadIdx.x;
    const int base = blockIdx.x * 4096;
#pragma unroll
    for (int j = 0; j < 4; j++) {
        const int p0 = base + j * 1024 + tid * 4;
        if (p0 + 3 < P) {
            int4 n4 = *(const int4*)(bidx + p0);
            const float4* xv = (const float4*)(x + 3 * (size_t)p0);
            float4 a = xv[0], b = xv[1], c = xv[2];
            const float xs[12] = {a.x, a.y, a.z, a.w, b.x, b.y, b.z, b.w,
                                  c.x, c.y, c.z, c.w};
            const unsigned nn[4] = {(unsigned)n4.x, (unsigned)n4.y,
                                    (unsigned)n4.z, (unsigned)n4.w};
#pragma unroll
            for (int u = 0; u < 4; u++) {
                const unsigned dst = atomicAdd(&cursor[nn[u]], 1u);
                xb[dst] = make_float4(xs[3 * u], xs[3 * u + 1], xs[3 * u + 2],
                                      __uint_as_float(nn[u]));
            }
        } else {
            for (int u = 0; u < 4; u++) {
                const int p = p0 + u;
                if (p < P) {
                    const unsigned n = (unsigned)bidx[p];
                    const unsigned dst = atomicAdd(&cursor[n], 1u);
                    xb[dst] = make_float4(x[3 * p], x[3 * p + 1], x[3 * p + 2],
                                          __uint_as_float(n));
                }
            }
        }
    }
}

// ---------------------------------------------------------------------------
// K4: fused MLP1 + chunk-segmented max pool — EXACT Round-5 measured-good
// version (92.6 µs, FETCH 17 MB / WRITE 18 MB, VALUBusy 58%). FROZEN.
// ---------------------------------------------------------------------------
__global__ __launch_bounds__(256, 3) void fused_mlp1_pool_kernel(
    const float4* __restrict__ xb, const unsigned* __restrict__ offsets,
    const float* __restrict__ pW1e, const float* __restrict__ pGB,
    const float* __restrict__ pSG, const unsigned short* __restrict__ pW2t,
    const float* __restrict__ b2,
    unsigned* __restrict__ segord, int P)
{
    __shared__ __align__(16) unsigned short shbt[64 * 260];  // 33.3 KB, [ch][row]
    __shared__ unsigned sn01[2];

    const int tid  = threadIdx.x;
    const int wv   = tid >> 6;
    const int lane = tid & 63;
    const int m    = lane & 15;
    const int quad = lane >> 4;
    const int base = blockIdx.x * 256;
    const int pos  = base + tid;
    const bool valid = (pos < P);

    // ---- W2 B-fragments + bias: straight from global into registers
    bf16x8 bfrag[4][2];
    float bc[4];
#pragma unroll
    for (int nt = 0; nt < 4; nt++) {
        bc[nt] = b2[nt * 16 + m];
#pragma unroll
        for (int s = 0; s < 2; s++)
            bfrag[nt][s] = *reinterpret_cast<const bf16x8*>(
                &pW2t[(nt * 16 + m) * 72 + s * 32 + quad * 8]);
    }

    // ---- own row load + LN stats via Gram trick
    float x0 = 0.f, x1 = 0.f, x2 = 0.f;
    if (valid) {
        float4 v = xb[pos];
        x0 = v.x; x1 = v.y; x2 = v.z;
        unsigned node = __float_as_uint(v.w);
        if (tid == 0) sn01[0] = node;
        if (tid == 255 || pos == P - 1) sn01[1] = node;
    }

    float rs, r2;
    {
        const float S0 = pSG[0], S1 = pSG[1], S2 = pSG[2], S3 = pSG[3];
        const float g00 = pSG[4], g01 = pSG[5], g02 = pSG[6], g03 = pSG[7];
        const float g11 = pSG[8], g12 = pSG[9], g13 = pSG[10];
        const float g22 = pSG[11], g23 = pSG[12], g33 = pSG[13];

        const float mu = fmaf(S0, x0, fmaf(S1, x1, fmaf(S2, x2, S3))) * (1.f / 64.f);
        float q = g33;
        q = fmaf(g00, x0 * x0, q);
        q = fmaf(g11, x1 * x1, q);
        q = fmaf(g22, x2 * x2, q);
        float c = fmaf(g01, x1, fmaf(g02, x2, g03));
        q = fmaf(2.f * x0, c, q);
        q = fmaf(2.f * x1, fmaf(g12, x2, g13), q);
        q = fmaf(2.f * x2, g23, q);
        float var = q * (1.f / 64.f) - mu * mu;
        var = var > 0.f ? var : 0.f;
        rs = rsqrtf(var + EPS_LN);
        r2 = -mu * rs;
    }

    // ---- deliver x/stats of the 4 rows this lane serves (wave-local rows)
    float xr0[4], xr1[4], xr2[4], rsr[4], r2r[4];
#pragma unroll
    for (int rt = 0; rt < 4; rt++) {
        const int src = rt * 16 + m;
        xr0[rt] = __shfl(x0, src);
        xr1[rt] = __shfl(x1, src);
        xr2[rt] = __shfl(x2, src);
        rsr[rt] = __shfl(rs, src);
        r2r[rt] = __shfl(r2, src);
    }

    // ---- Phase 1: layer-1 + LN + ReLU, computed directly in A-frag layout.
    u32x4 afr[4][2];
    {
        const float4* pw = (const float4*)pW1e;
        const float2* pg = (const float2*)pGB;
#pragma unroll
        for (int s = 0; s < 2; s++) {
#pragma unroll
            for (int up = 0; up < 4; up++) {
                const int ch = s * 32 + quad * 8 + up * 2;
                const float4 wA = pw[ch], wB = pw[ch + 1];
                const float2 gA = pg[ch], gB = pg[ch + 1];
#pragma unroll
                for (int rt = 0; rt < 4; rt++) {
                    float y0 = fmaf(xr0[rt], wA.x, fmaf(xr1[rt], wA.y,
                               fmaf(xr2[rt], wA.z, wA.w)));
                    float y1 = fmaf(xr0[rt], wB.x, fmaf(xr1[rt], wB.y,
                               fmaf(xr2[rt], wB.z, wB.w)));
                    float a0 = fmaf(fmaf(y0, rsr[rt], r2r[rt]), gA.x, gA.y);
                    float a1 = fmaf(fmaf(y1, rsr[rt], r2r[rt]), gB.x, gB.y);
                    a0 = a0 > 0.f ? a0 : 0.f;
                    a1 = a1 > 0.f ? a1 : 0.f;
                    afr[rt][s][up] = (unsigned)f2bf(a0) | ((unsigned)f2bf(a1) << 16);
                }
            }
        }
    }

    // ---- Phase 2: h = a @ W2 + b2 via MFMA; transposed ordkey16 store
#pragma unroll
    for (int rt = 0; rt < 4; rt++) {
        const int orow = wv * 64 + rt * 16 + quad * 4;   // C rows this lane owns
        const bf16x8 af0 = __builtin_bit_cast(bf16x8, afr[rt][0]);
        const bf16x8 af1 = __builtin_bit_cast(bf16x8, afr[rt][1]);
#pragma unroll
        for (int nt = 0; nt < 4; nt++) {
            f32x4 acc = {bc[nt], bc[nt], bc[nt], bc[nt]};
            acc = __builtin_amdgcn_mfma_f32_16x16x32_bf16(af0, bfrag[nt][0], acc, 0, 0, 0);
            acc = __builtin_amdgcn_mfma_f32_16x16x32_bf16(af1, bfrag[nt][1], acc, 0, 0, 0);
            const int col = nt * 16 + m;
            uint2 pk;
            pk.x = (unsigned)ok16(acc[0]) | ((unsigned)ok16(acc[1]) << 16);
            pk.y = (unsigned)ok16(acc[2]) | ((unsigned)ok16(acc[3]) << 16);
            *reinterpret_cast<uint2*>(&shbt[col * 260 + orow]) = pk;
        }
    }
    __syncthreads();

    // ---- Phase 3: segmented max, contiguous b64 reads + packed u16 max
    const int nValid = (P - base < 256) ? (P - base) : 256;
    if (nValid <= 0) return;
    const unsigned n0 = sn01[0];
    const unsigned n1 = sn01[1];
    const unsigned bEnd = (unsigned)(base + nValid);
    const int wave = tid >> 6;
    const int ch   = tid & 63;
    const unsigned short* rowp = &shbt[ch * 260];

    for (unsigned n = n0 + (unsigned)wave; n <= n1; n += 4) {
        const unsigned s = offsets[n];
        const unsigned e = offsets[n + 1];
        int lo = (int)(s > (unsigned)base ? s : (unsigned)base) - base;
        int hi = (int)(e < bEnd ? e : bEnd) - base;
        if (hi <= lo) continue;   // empty node inside range: leave 0
        u16x2 accv = {0, 0};
        unsigned short accs = 0;
        for (int r = lo & ~3; r < hi; r += 4) {
            uint2 d = *reinterpret_cast<const uint2*>(rowp + r);
            if (r >= lo && r + 4 <= hi) {
                u16x2 a = __builtin_bit_cast(u16x2, d.x);
                u16x2 b = __builtin_bit_cast(u16x2, d.y);
                accv = __builtin_elementwise_max(accv, __builtin_elementwise_max(a, b));
            } else {
                unsigned short v0 = (unsigned short)(d.x & 0xFFFFu);
                unsigned short v1 = (unsigned short)(d.x >> 16);
                unsigned short v2 = (unsigned short)(d.y & 0xFFFFu);
                unsigned short v3 = (unsigned short)(d.y >> 16);
                if (r     >= lo && r     < hi && v0 > accs) accs = v0;
                if (r + 1 >= lo && r + 1 < hi && v1 > accs) accs = v1;
                if (r + 2 >= lo && r + 2 < hi && v2 > accs) accs = v2;
                if (r + 3 >= lo && r + 3 < hi && v3 > accs) accs = v3;
            }
        }
        unsigned short k = accv.x > accv.y ? accv.x : accv.y;
        if (accs > k) k = accs;
        const unsigned key = ((unsigned)k) << 16;
        unsigned* dst = &segord[(size_t)n * 64 + ch];
        if (s >= (unsigned)base && e <= bEnd) *dst = key;   // sole writer
        else atomicMax(dst, key);                            // boundary node
    }
}

// ---------------------------------------------------------------------------
// K5: MLP2 fully in MFMA with split-bf16. Grid 512 (measured better than
// 2048 in R5: non-fused residual 244.8 -> 257.5 µs with 2048).
// ---------------------------------------------------------------------------
__global__ __launch_bounds__(256) void mlp2_mfma_kernel(
    const unsigned* __restrict__ segord,
    const unsigned short* __restrict__ W3th, const unsigned short* __restrict__ W3tl,
    const unsigned short* __restrict__ W4th, const unsigned short* __restrict__ W4tl,
    const float* __restrict__ b3, const float* __restrict__ g2,
    const float* __restrict__ be2, const float* __restrict__ b4,
    float* __restrict__ out, int N)
{
    __shared__ __align__(16) unsigned short sa2[32 * 72];
    __shared__ __align__(16) float st[32 * 132];
    __shared__ __align__(16) unsigned short suh[32 * 136];
    __shared__ __align__(16) unsigned short sul[32 * 136];
    __shared__ float2 sred[32][8];
    __shared__ float sg2[128], sbe2[128];

    const int tid  = threadIdx.x;
    const int wv   = tid >> 6;
    const int lane = tid & 63;
    const int m    = lane & 15;
    const int quad = lane >> 4;

    if (tid < 128) { sg2[tid] = g2[tid]; sbe2[tid] = be2[tid]; }

    bf16x8 fw3h[2][2], fw3l[2][2];
    bf16x8 fw4h[2][4], fw4l[2][4];
    float bias3[2], bias4[2];
#pragma unroll
    for (int nti = 0; nti < 2; nti++) {
        const int nrow = (wv * 2 + nti) * 16 + m;
        bias3[nti] = b3[nrow];
        bias4[nti] = b4[nrow];
#pragma unroll
        for (int ks = 0; ks < 2; ks++) {
            fw3h[nti][ks] = *reinterpret_cast<const bf16x8*>(&W3th[nrow * 64 + ks * 32 + quad * 8]);
            fw3l[nti][ks] = *reinterpret_cast<const bf16x8*>(&W3tl[nrow * 64 + ks * 32 + quad * 8]);
        }
#pragma unroll
        for (int ks = 0; ks < 4; ks++) {
            fw4h[nti][ks] = *reinterpret_cast<const bf16x8*>(&W4th[nrow * 128 + ks * 32 + quad * 8]);
            fw4l[nti][ks] = *reinterpret_cast<const bf16x8*>(&W4tl[nrow * 128 + ks * 32 + quad * 8]);
        }
    }
    __syncthreads();

    for (int nb = blockIdx.x * 32; nb < N; nb += gridDim.x * 32) {
        {
            const int node = tid >> 3;
            const int k8   = (tid & 7) * 8;
            const uint4* sp = (const uint4*)&segord[(size_t)(nb + node) * 64 + k8];
            uint4 q0 = sp[0], q1 = sp[1];
            bf16x8 v;
            v[0] = (short)f2bf(decseg(q0.x));
            v[1] = (short)f2bf(decseg(q0.y));
            v[2] = (short)f2bf(decseg(q0.z));
            v[3] = (short)f2bf(decseg(q0.w));
            v[4] = (short)f2bf(decseg(q1.x));
            v[5] = (short)f2bf(decseg(q1.y));
            v[6] = (short)f2bf(decseg(q1.z));
            v[7] = (short)f2bf(decseg(q1.w));
            *reinterpret_cast<bf16x8*>(&sa2[node * 72 + k8]) = v;
        }
        __syncthreads();

#pragma unroll
        for (int mt = 0; mt < 2; mt++) {
            bf16x8 a0 = *reinterpret_cast<const bf16x8*>(&sa2[(mt * 16 + m) * 72 + quad * 8]);
            bf16x8 a1 = *reinterpret_cast<const bf16x8*>(&sa2[(mt * 16 + m) * 72 + 32 + quad * 8]);
#pragma unroll
            for (int nti = 0; nti < 2; nti++) {
                f32x4 acc = {bias3[nti], bias3[nti], bias3[nti], bias3[nti]};
                acc = __builtin_amdgcn_mfma_f32_16x16x32_bf16(a0, fw3h[nti][0], acc, 0, 0, 0);
                acc = __builtin_amdgcn_mfma_f32_16x16x32_bf16(a1, fw3h[nti][1], acc, 0, 0, 0);
                acc = __builtin_amdgcn_mfma_f32_16x16x32_bf16(a0, fw3l[nti][0], acc, 0, 0, 0);
                acc = __builtin_amdgcn_mfma_f32_16x16x32_bf16(a1, fw3l[nti][1], acc, 0, 0, 0);
#pragma unroll
                for (int r = 0; r < 4; r++)
                    st[(mt * 16 + quad * 4 + r) * 132 + (wv * 2 + nti) * 16 + m] = acc[r];
            }
        }
        __syncthreads();

        {
            const int node = tid >> 3;
            const int seg  = tid & 7;
            const float4* rp = (const float4*)&st[node * 132 + seg * 16];
            float4 v0 = rp[0], v1 = rp[1], v2 = rp[2], v3 = rp[3];
            float s1 = v0.x + v0.y + v0.z + v0.w + v1.x + v1.y + v1.z + v1.w
                     + v2.x + v2.y + v2.z + v2.w + v3.x + v3.y + v3.z + v3.w;
            float s2 = 0.f;
            s2 = fmaf(v0.x, v0.x, s2); s2 = fmaf(v0.y, v0.y, s2); s2 = fmaf(v0.z, v0.z, s2); s2 = fmaf(v0.w, v0.w, s2);
            s2 = fmaf(v1.x, v1.x, s2); s2 = fmaf(v1.y, v1.y, s2); s2 = fmaf(v1.z, v1.z, s2); s2 = fmaf(v1.w, v1.w, s2);
            s2 = fmaf(v2.x, v2.x, s2); s2 = fmaf(v2.y, v2.y, s2); s2 = fmaf(v2.z, v2.z, s2); s2 = fmaf(v2.w, v2.w, s2);
            s2 = fmaf(v3.x, v3.x, s2); s2 = fmaf(v3.y, v3.y, s2); s2 = fmaf(v3.z, v3.z, s2); s2 = fmaf(v3.w, v3.w, s2);
            sred[node][seg] = make_float2(s1, s2);
            __syncthreads();

            float t1 = 0.f, t2 = 0.f;
#pragma unroll
            for (int i = 0; i < 8; i++) { float2 r = sred[node][i]; t1 += r.x; t2 += r.y; }
            const float mu  = t1 * (1.f / 128.f);
            float var = t2 * (1.f / 128.f) - mu * mu;
            var = var > 0.f ? var : 0.f;
            const float rsd = rsqrtf(var + EPS_LN);

            float tv[16] = {v0.x, v0.y, v0.z, v0.w, v1.x, v1.y, v1.z, v1.w,
                            v2.x, v2.y, v2.z, v2.w, v3.x, v3.y, v3.z, v3.w};
            bf16x8 vh[2], vl[2];
#pragma unroll
            for (int i = 0; i < 16; i++) {
                const int j = seg * 16 + i;
                float u = fmaf((tv[i] - mu) * rsd, sg2[j], sbe2[j]);
                u = u > 0.f ? u : 0.f;
                unsigned short uh = f2bf(u);
                unsigned short ul = f2bf(u - bf2f(uh));
                vh[i >> 3][i & 7] = (short)uh;
                vl[i >> 3][i & 7] = (short)ul;
            }
            *reinterpret_cast<bf16x8*>(&suh[node * 136 + seg * 16])     = vh[0];
            *reinterpret_cast<bf16x8*>(&suh[node * 136 + seg * 16 + 8]) = vh[1];
            *reinterpret_cast<bf16x8*>(&sul[node * 136 + seg * 16])     = vl[0];
            *reinterpret_cast<bf16x8*>(&sul[node * 136 + seg * 16 + 8]) = vl[1];
        }
        __syncthreads();

#pragma unroll
        for (int mt = 0; mt < 2; mt++) {
            bf16x8 ah[4], al[4];
#pragma unroll
            for (int ks = 0; ks < 4; ks++) {
                ah[ks] = *reinterpret_cast<const bf16x8*>(&suh[(mt * 16 + m) * 136 + ks * 32 + quad * 8]);
                al[ks] = *reinterpret_cast<const bf16x8*>(&sul[(mt * 16 + m) * 136 + ks * 32 + quad * 8]);
            }
#pragma unroll
            for (int nti = 0; nti < 2; nti++) {
                f32x4 acc = {bias4[nti], bias4[nti], bias4[nti], bias4[nti]};
#pragma unroll
                for (int ks = 0; ks < 4; ks++) {
                    acc = __builtin_amdgcn_mfma_f32_16x16x32_bf16(ah[ks], fw4h[nti][ks], acc, 0, 0, 0);
                    acc = __builtin_amdgcn_mfma_f32_16x16x32_bf16(al[ks], fw4h[nti][ks], acc, 0, 0, 0);
                    acc = __builtin_amdgcn_mfma_f32_16x16x32_bf16(ah[ks], fw4l[nti][ks], acc, 0, 0, 0);
                }
#pragma unroll
                for (int r = 0; r < 4; r++) {
                    const int node = nb + mt * 16 + quad * 4 + r;
                    if (node < N)
                        out[(size_t)node * 128 + (wv * 2 + nti) * 16 + m] = acc[r];
                }
            }
        }
        __syncthreads();
    }
}

extern "C" void kernel_launch(void* const* d_in, const int* in_sizes, int n_in,
                              void* d_out, int out_size, void* d_ws, size_t ws_size,
                              hipStream_t stream) {
    const float* x    = (const float*)d_in[0];
    const int*   bidx = (const int*)d_in[1];
    const float* W1  = (const float*)d_in[3];
    const float* b1  = (const float*)d_in[4];
    const float* g1  = (const float*)d_in[5];
    const float* be1 = (const float*)d_in[6];
    const float* W2  = (const float*)d_in[7];
    const float* b2  = (const float*)d_in[8];
    const float* W3  = (const float*)d_in[9];
    const float* b3  = (const float*)d_in[10];
    const float* g2  = (const float*)d_in[11];
    const float* be2 = (const float*)d_in[12];
    const float* W4  = (const float*)d_in[13];
    const float* b4  = (const float*)d_in[14];

    const int P = in_sizes[0] / 3;
    const int N = out_size / 128;
    const int nblkC = (P + 1023) / 1024;       // c1: 1024 points/block
    const int nblkS = (P + 4095) / 4096;       // c3: 4096 points/block

    uintptr_t w = (uintptr_t)d_ws;
    auto align = [](uintptr_t v) { return (v + 255) & ~(uintptr_t)255; };
    unsigned* nodeCount = (unsigned*)align(w);     w = (uintptr_t)(nodeCount + N);
    unsigned* cursor    = (unsigned*)align(w);     w = (uintptr_t)(cursor    + N);
    unsigned* offsets   = (unsigned*)align(w);     w = (uintptr_t)(offsets   + N + 1);
    float4*   xb        = (float4*)align(w);       w = (uintptr_t)(xb        + P);
    unsigned* segord    = (unsigned*)align(w);     w = (uintptr_t)(segord    + (size_t)N * 64);
    float*    pW1e      = (float*)align(w);        w = (uintptr_t)(pW1e      + 256);
    float*    pGB       = (float*)align(w);        w = (uintptr_t)(pGB       + 128);
    float*    pSG       = (float*)align(w);        w = (uintptr_t)(pSG       + 16);
    unsigned short* pW2t = (unsigned short*)align(w); w = (uintptr_t)(pW2t + 64 * 72);
    unsigned short* W3th = (unsigned short*)align(w); w = (uintptr_t)(W3th + 128 * 64);
    unsigned short* W3tl = (unsigned short*)align(w); w = (uintptr_t)(W3tl + 128 * 64);
    unsigned short* W4th = (unsigned short*)align(w); w = (uintptr_t)(W4th + 128 * 128);
    unsigned short* W4tl = (unsigned short*)align(w); w = (uintptr_t)(W4tl + 128 * 128);

    hipMemsetAsync(nodeCount, 0, (size_t)N * sizeof(unsigned), stream);
    hipMemsetAsync(segord, 0, (size_t)N * 64 * sizeof(unsigned), stream);

    prep_kernel<<<1, 256, 0, stream>>>(W1, b1, g1, be1, W2, W3, W4,
                                       pW1e, pGB, pSG, pW2t, W3th, W3tl, W4th, W4tl);

    c1_count<<<nblkC, 256, 0, stream>>>(bidx, nodeCount, P);
    c2_scan<<<1, 1024, 0, stream>>>(nodeCount, offsets, cursor, N, P);
    c3_scatter<<<nblkS, 256, 0, stream>>>(bidx, x, cursor, xb, P);

    fused_mlp1_pool_kernel<<<(P + 255) / 256, 256, 0, stream>>>(
        xb, offsets, pW1e, pGB, pSG, pW2t, b2, segord, P);

    mlp2_mfma_kernel<<<512, 256, 0, stream>>>(
        segord, W3th, W3tl, W4th, W4tl, b3, g2, be2, b4, (float*)d_out, N);
}

// Round 7
// 335.397 us; speedup vs baseline: 1.8783x; 1.8783x over previous
//
#include <hip/hip_runtime.h>
#include <hip/hip_bf16.h>
#include <math.h>

#define EPS_LN 1e-5f

typedef __attribute__((ext_vector_type(8))) short bf16x8;
typedef __attribute__((ext_vector_type(4))) float f32x4;
typedef __attribute__((ext_vector_type(2))) unsigned short u16x2;
typedef __attribute__((ext_vector_type(4))) unsigned int u32x4;

__device__ __forceinline__ unsigned short f2bf(float f) {
    __hip_bfloat16 h = __float2bfloat16(f);
    return *reinterpret_cast<unsigned short*>(&h);
}
__device__ __forceinline__ float bf2f(unsigned short u) {
    return __uint_as_float(((unsigned)u) << 16);
}
// monotone 16-bit key of a bf16 pattern; 0 is below all real values
__device__ __forceinline__ unsigned short ok16(float f) {
    unsigned short t = f2bf(f);
    unsigned short mask = (unsigned short)(((short)t) >> 15);
    return (unsigned short)(t ^ (unsigned short)(mask | 0x8000u));
}
// decode segord entry (key16<<16; 0 == empty -> 0.0)
__device__ __forceinline__ float decseg(unsigned o) {
    if (o == 0u) return 0.f;
    unsigned k = o >> 16;
    unsigned h = (k & 0x8000u) ? (k & 0x7FFFu) : (~k & 0xFFFFu);
    return bf2f((unsigned short)h);
}

// ---------------------------------------------------------------------------
// K0: prep — pack params once per call.
// ---------------------------------------------------------------------------
__global__ __launch_bounds__(256) void prep_kernel(
    const float* __restrict__ W1, const float* __restrict__ b1,
    const float* __restrict__ g1, const float* __restrict__ be1,
    const float* __restrict__ W2,
    const float* __restrict__ W3, const float* __restrict__ W4,
    float* __restrict__ pW1e, float* __restrict__ pGB, float* __restrict__ pSG,
    unsigned short* __restrict__ pW2t,
    unsigned short* __restrict__ W3th, unsigned short* __restrict__ W3tl,
    unsigned short* __restrict__ W4th, unsigned short* __restrict__ W4tl)
{
    const int tid = threadIdx.x;
    if (tid < 64) {
        pW1e[4 * tid + 0] = W1[tid];
        pW1e[4 * tid + 1] = W1[64 + tid];
        pW1e[4 * tid + 2] = W1[128 + tid];
        pW1e[4 * tid + 3] = b1[tid];
        pGB[2 * tid + 0] = g1[tid];
        pGB[2 * tid + 1] = be1[tid];
    }
    if (tid >= 64 && tid < 78) {
        const int t = tid - 64;
        auto wcomp = [&](int k, int i) -> float {
            return (i < 3) ? W1[i * 64 + k] : b1[k];
        };
        if (t < 4) {
            float s = 0.f;
            for (int k = 0; k < 64; k++) s += wcomp(k, t);
            pSG[t] = s;
        } else {
            const int pi[10] = {0,0,0,0,1,1,1,2,2,3};
            const int pj[10] = {0,1,2,3,1,2,3,2,3,3};
            int p = t - 4;
            float s = 0.f;
            for (int k = 0; k < 64; k++) s += wcomp(k, pi[p]) * wcomp(k, pj[p]);
            pSG[4 + p] = s;
        }
    }
    for (int i = tid; i < 4096; i += 256) {
        int k = i >> 6, n = i & 63;
        pW2t[n * 72 + k] = f2bf(W2[i]);
    }
    for (int i = tid; i < 64 * 8; i += 256) {
        int n = i >> 3, k = 64 + (i & 7);
        pW2t[n * 72 + k] = 0;
    }
    for (int i = tid; i < 8192; i += 256) {
        int k = i >> 7, n = i & 127;
        float w = W3[k * 128 + n];
        unsigned short h = f2bf(w);
        W3th[n * 64 + k] = h;
        W3tl[n * 64 + k] = f2bf(w - bf2f(h));
    }
    for (int i = tid; i < 16384; i += 256) {
        int k = i >> 7, n = i & 127;
        float w = W4[k * 128 + n];
        unsigned short h = f2bf(w);
        W4th[n * 128 + k] = h;
        W4tl[n * 128 + k] = f2bf(w - bf2f(h));
    }
}

// ---------------------------------------------------------------------------
// Sort stage 1: per-block LDS hist over 2048 partitions (node>>5).
// NO global atomics. (R1 measured-good pipeline, restored after R6's
// global-atomic scatter regressed: returning atomics + 4x write-amp.)
// ---------------------------------------------------------------------------
__global__ __launch_bounds__(256) void s1_count(const int* __restrict__ bidx,
                                                unsigned* __restrict__ blockHist, int P) {
    __shared__ unsigned hist[2048];
    const int tid = threadIdx.x;
    for (int i = tid; i < 2048; i += 256) hist[i] = 0;
    __syncthreads();
    const int base = blockIdx.x * 4096;
#pragma unroll
    for (int j = 0; j < 4; j++) {
        const int p0 = base + j * 1024 + tid * 4;
        if (p0 + 3 < P) {
            int4 n4 = *(const int4*)(bidx + p0);
            atomicAdd(&hist[((unsigned)n4.x) >> 5], 1u);
            atomicAdd(&hist[((unsigned)n4.y) >> 5], 1u);
            atomicAdd(&hist[((unsigned)n4.z) >> 5], 1u);
            atomicAdd(&hist[((unsigned)n4.w) >> 5], 1u);
        } else {
            for (int p = p0; p < P && p < p0 + 4; p++)
                atomicAdd(&hist[((unsigned)bidx[p]) >> 5], 1u);
        }
    }
    __syncthreads();
    unsigned* dst = blockHist + (size_t)blockIdx.x * 2048;
    for (int i = tid; i < 2048; i += 256) dst[i] = hist[i];
}

// ---------------------------------------------------------------------------
// Sort stage 2a: binTotal[bin] = sum over blocks. One block per bin.
// ---------------------------------------------------------------------------
__global__ __launch_bounds__(256) void s2a_total(const unsigned* __restrict__ blockHist,
                                                 unsigned* __restrict__ binTotal, int nblk) {
    const int bin = blockIdx.x;
    const int tid = threadIdx.x;
    unsigned s = 0;
    for (int b = tid; b < nblk; b += 256) s += blockHist[(size_t)b * 2048 + bin];
    for (int off = 32; off; off >>= 1) s += __shfl_down(s, off);
    __shared__ unsigned ws[4];
    if ((tid & 63) == 0) ws[tid >> 6] = s;
    __syncthreads();
    if (tid == 0) binTotal[bin] = ws[0] + ws[1] + ws[2] + ws[3];
}

// ---------------------------------------------------------------------------
// Sort stage 2b: exclusive scan of binTotal -> partBase[nparts+1]. 1 block.
// ---------------------------------------------------------------------------
__global__ __launch_bounds__(1024) void s2b_scan(const unsigned* __restrict__ binTotal,
                                                 unsigned* __restrict__ partBase,
                                                 int nparts, int P) {
    __shared__ unsigned wtot[16];
    const int t = threadIdx.x;
    const unsigned c0 = (2 * t < nparts) ? binTotal[2 * t] : 0u;
    const unsigned c1 = (2 * t + 1 < nparts) ? binTotal[2 * t + 1] : 0u;
    const unsigned s = c0 + c1;
    unsigned v = s;
    const int lane = t & 63;
    for (int off = 1; off < 64; off <<= 1) {
        unsigned u = __shfl_up(v, off);
        if (lane >= off) v += u;
    }
    if (lane == 63) wtot[t >> 6] = v;
    __syncthreads();
    if (t == 0) {
        unsigned a = 0;
        for (int w = 0; w < 16; w++) { unsigned tmp = wtot[w]; wtot[w] = a; a += tmp; }
    }
    __syncthreads();
    const unsigned excl = wtot[t >> 6] + (v - s);
    if (2 * t < nparts) partBase[2 * t] = excl;
    if (2 * t + 1 < nparts) partBase[2 * t + 1] = excl + c0;
    if (t == 0) partBase[nparts] = (unsigned)P;
}

// ---------------------------------------------------------------------------
// Sort stage 2c: per-(block,bin) cursor, IN PLACE over blockHist.
// ---------------------------------------------------------------------------
__global__ __launch_bounds__(256) void s2c_cursor(unsigned* __restrict__ blockHist,
                                                  const unsigned* __restrict__ partBase,
                                                  int nblk) {
    __shared__ unsigned wt0[4], wb0[4], wt1[4], wb1[4], tot0s;
    const int bin = blockIdx.x;
    const int tid = threadIdx.x;
    const int lane = tid & 63;
    const unsigned c0 = (tid < nblk) ? blockHist[(size_t)tid * 2048 + bin] : 0u;
    const unsigned c1 = (tid + 256 < nblk) ? blockHist[(size_t)(tid + 256) * 2048 + bin] : 0u;

    unsigned v0 = c0;
    for (int off = 1; off < 64; off <<= 1) {
        unsigned u = __shfl_up(v0, off);
        if (lane >= off) v0 += u;
    }
    if (lane == 63) wt0[tid >> 6] = v0;
    unsigned v1 = c1;
    for (int off = 1; off < 64; off <<= 1) {
        unsigned u = __shfl_up(v1, off);
        if (lane >= off) v1 += u;
    }
    if (lane == 63) wt1[tid >> 6] = v1;
    __syncthreads();
    if (tid == 0) {
        unsigned a = 0;
        for (int i = 0; i < 4; i++) { unsigned tmp = wt0[i]; wb0[i] = a; a += tmp; }
        tot0s = a;
        a = 0;
        for (int i = 0; i < 4; i++) { unsigned tmp = wt1[i]; wb1[i] = a; a += tmp; }
    }
    __syncthreads();
    const unsigned pb = partBase[bin];
    const unsigned e0 = pb + wb0[tid >> 6] + (v0 - c0);
    const unsigned e1 = pb + tot0s + wb1[tid >> 6] + (v1 - c1);
    if (tid < nblk) blockHist[(size_t)tid * 2048 + bin] = e0;
    if (tid + 256 < nblk) blockHist[(size_t)(tid + 256) * 2048 + bin] = e1;
}

// ---------------------------------------------------------------------------
// Sort stage 3: scatter (x,node) float4 into partition-grouped xb using
// precomputed deterministic cursors (LDS-local atomics only).
// ---------------------------------------------------------------------------
__global__ __launch_bounds__(256) void s3_scatter(const int* __restrict__ bidx,
                                                  const float* __restrict__ x,
                                                  const unsigned* __restrict__ blockCursor,
                                                  float4* __restrict__ xb, int P) {
    __shared__ unsigned cur[2048];
    const int tid = threadIdx.x;
    const unsigned* src = blockCursor + (size_t)blockIdx.x * 2048;
    for (int i = tid; i < 2048; i += 256) cur[i] = src[i];
    __syncthreads();
    const int base = blockIdx.x * 4096;
#pragma unroll
    for (int j = 0; j < 4; j++) {
        const int p0 = base + j * 1024 + tid * 4;
        if (p0 + 3 < P) {
            int4 n4 = *(const int4*)(bidx + p0);
            const float4* xv = (const float4*)(x + 3 * (size_t)p0);
            float4 a = xv[0], b = xv[1], c = xv[2];
            const float xs[12] = {a.x, a.y, a.z, a.w, b.x, b.y, b.z, b.w,
                                  c.x, c.y, c.z, c.w};
            const unsigned nn[4] = {(unsigned)n4.x, (unsigned)n4.y,
                                    (unsigned)n4.z, (unsigned)n4.w};
#pragma unroll
            for (int u = 0; u < 4; u++) {
                const unsigned dst = atomicAdd(&cur[nn[u] >> 5], 1u);
                xb[dst] = make_float4(xs[3 * u], xs[3 * u + 1], xs[3 * u + 2],
                                      __uint_as_float(nn[u]));
            }
        } else {
            for (int u = 0; u < 4; u++) {
                const int p = p0 + u;
                if (p < P) {
                    const unsigned n = (unsigned)bidx[p];
                    const unsigned dst = atomicAdd(&cur[n >> 5], 1u);
                    xb[dst] = make_float4(x[3 * p], x[3 * p + 1], x[3 * p + 2],
                                          __uint_as_float(n));
                }
            }
        }
    }
}

// ---------------------------------------------------------------------------
// Sort stage 4: per-partition CSR + node-sort. One block per partition.
// ---------------------------------------------------------------------------
__global__ __launch_bounds__(256) void s4_csr(const unsigned* __restrict__ partBase,
                                              unsigned* __restrict__ offsets,
                                              float4* __restrict__ xb, int N) {
    __shared__ float4 stage[1600];
    __shared__ unsigned hist[32], cur[32];
    const int tid = threadIdx.x;
    const int p = blockIdx.x;
    const unsigned start = partBase[p], end = partBase[p + 1];
    unsigned cnt = end - start;
    if (cnt > 1600u) cnt = 1600u;
    if (tid < 32) hist[tid] = 0;
    __syncthreads();
    for (unsigned k = tid; k < cnt; k += 256) {
        float4 r = xb[start + k];
        stage[k] = r;
        atomicAdd(&hist[__float_as_uint(r.w) & 31u], 1u);
    }
    __syncthreads();
    if (tid < 64) {
        const unsigned c = (tid < 32) ? hist[tid] : 0u;
        unsigned v = c;
        for (int off = 1; off < 32; off <<= 1) {
            unsigned u = __shfl_up(v, off);
            if (tid >= off) v += u;
        }
        if (tid < 32) {
            const unsigned excl = v - c;
            const int node = p * 32 + tid;
            if (node < N) offsets[node] = start + excl;
            cur[tid] = start + excl;
            if (node == N - 1) offsets[N] = start + excl + c;
        }
    }
    __syncthreads();
    for (unsigned k = tid; k < cnt; k += 256) {
        float4 r = stage[k];
        const unsigned dst = atomicAdd(&cur[__float_as_uint(r.w) & 31u], 1u);
        xb[dst] = r;
    }
}

// ---------------------------------------------------------------------------
// K4: fused MLP1 + chunk-segmented max pool — EXACT Round-5 measured-good
// version (92.6 µs, FETCH 17 MB / WRITE 18 MB, VALUBusy 58%). FROZEN.
// ---------------------------------------------------------------------------
__global__ __launch_bounds__(256, 3) void fused_mlp1_pool_kernel(
    const float4* __restrict__ xb, const unsigned* __restrict__ offsets,
    const float* __restrict__ pW1e, const float* __restrict__ pGB,
    const float* __restrict__ pSG, const unsigned short* __restrict__ pW2t,
    const float* __restrict__ b2,
    unsigned* __restrict__ segord, int P)
{
    __shared__ __align__(16) unsigned short shbt[64 * 260];  // 33.3 KB, [ch][row]
    __shared__ unsigned sn01[2];

    const int tid  = threadIdx.x;
    const int wv   = tid >> 6;
    const int lane = tid & 63;
    const int m    = lane & 15;
    const int quad = lane >> 4;
    const int base = blockIdx.x * 256;
    const int pos  = base + tid;
    const bool valid = (pos < P);

    // ---- W2 B-fragments + bias: straight from global into registers
    bf16x8 bfrag[4][2];
    float bc[4];
#pragma unroll
    for (int nt = 0; nt < 4; nt++) {
        bc[nt] = b2[nt * 16 + m];
#pragma unroll
        for (int s = 0; s < 2; s++)
            bfrag[nt][s] = *reinterpret_cast<const bf16x8*>(
                &pW2t[(nt * 16 + m) * 72 + s * 32 + quad * 8]);
    }

    // ---- own row load + LN stats via Gram trick
    float x0 = 0.f, x1 = 0.f, x2 = 0.f;
    if (valid) {
        float4 v = xb[pos];
        x0 = v.x; x1 = v.y; x2 = v.z;
        unsigned node = __float_as_uint(v.w);
        if (tid == 0) sn01[0] = node;
        if (tid == 255 || pos == P - 1) sn01[1] = node;
    }

    float rs, r2;
    {
        const float S0 = pSG[0], S1 = pSG[1], S2 = pSG[2], S3 = pSG[3];
        const float g00 = pSG[4], g01 = pSG[5], g02 = pSG[6], g03 = pSG[7];
        const float g11 = pSG[8], g12 = pSG[9], g13 = pSG[10];
        const float g22 = pSG[11], g23 = pSG[12], g33 = pSG[13];

        const float mu = fmaf(S0, x0, fmaf(S1, x1, fmaf(S2, x2, S3))) * (1.f / 64.f);
        float q = g33;
        q = fmaf(g00, x0 * x0, q);
        q = fmaf(g11, x1 * x1, q);
        q = fmaf(g22, x2 * x2, q);
        float c = fmaf(g01, x1, fmaf(g02, x2, g03));
        q = fmaf(2.f * x0, c, q);
        q = fmaf(2.f * x1, fmaf(g12, x2, g13), q);
        q = fmaf(2.f * x2, g23, q);
        float var = q * (1.f / 64.f) - mu * mu;
        var = var > 0.f ? var : 0.f;
        rs = rsqrtf(var + EPS_LN);
        r2 = -mu * rs;
    }

    // ---- deliver x/stats of the 4 rows this lane serves (wave-local rows)
    float xr0[4], xr1[4], xr2[4], rsr[4], r2r[4];
#pragma unroll
    for (int rt = 0; rt < 4; rt++) {
        const int src = rt * 16 + m;
        xr0[rt] = __shfl(x0, src);
        xr1[rt] = __shfl(x1, src);
        xr2[rt] = __shfl(x2, src);
        rsr[rt] = __shfl(rs, src);
        r2r[rt] = __shfl(r2, src);
    }

    // ---- Phase 1: layer-1 + LN + ReLU, computed directly in A-frag layout.
    u32x4 afr[4][2];
    {
        const float4* pw = (const float4*)pW1e;
        const float2* pg = (const float2*)pGB;
#pragma unroll
        for (int s = 0; s < 2; s++) {
#pragma unroll
            for (int up = 0; up < 4; up++) {
                const int ch = s * 32 + quad * 8 + up * 2;
                const float4 wA = pw[ch], wB = pw[ch + 1];
                const float2 gA = pg[ch], gB = pg[ch + 1];
#pragma unroll
                for (int rt = 0; rt < 4; rt++) {
                    float y0 = fmaf(xr0[rt], wA.x, fmaf(xr1[rt], wA.y,
                               fmaf(xr2[rt], wA.z, wA.w)));
                    float y1 = fmaf(xr0[rt], wB.x, fmaf(xr1[rt], wB.y,
                               fmaf(xr2[rt], wB.z, wB.w)));
                    float a0 = fmaf(fmaf(y0, rsr[rt], r2r[rt]), gA.x, gA.y);
                    float a1 = fmaf(fmaf(y1, rsr[rt], r2r[rt]), gB.x, gB.y);
                    a0 = a0 > 0.f ? a0 : 0.f;
                    a1 = a1 > 0.f ? a1 : 0.f;
                    afr[rt][s][up] = (unsigned)f2bf(a0) | ((unsigned)f2bf(a1) << 16);
                }
            }
        }
    }

    // ---- Phase 2: h = a @ W2 + b2 via MFMA; transposed ordkey16 store
#pragma unroll
    for (int rt = 0; rt < 4; rt++) {
        const int orow = wv * 64 + rt * 16 + quad * 4;   // C rows this lane owns
        const bf16x8 af0 = __builtin_bit_cast(bf16x8, afr[rt][0]);
        const bf16x8 af1 = __builtin_bit_cast(bf16x8, afr[rt][1]);
#pragma unroll
        for (int nt = 0; nt < 4; nt++) {
            f32x4 acc = {bc[nt], bc[nt], bc[nt], bc[nt]};
            acc = __builtin_amdgcn_mfma_f32_16x16x32_bf16(af0, bfrag[nt][0], acc, 0, 0, 0);
            acc = __builtin_amdgcn_mfma_f32_16x16x32_bf16(af1, bfrag[nt][1], acc, 0, 0, 0);
            const int col = nt * 16 + m;
            uint2 pk;
            pk.x = (unsigned)ok16(acc[0]) | ((unsigned)ok16(acc[1]) << 16);
            pk.y = (unsigned)ok16(acc[2]) | ((unsigned)ok16(acc[3]) << 16);
            *reinterpret_cast<uint2*>(&shbt[col * 260 + orow]) = pk;
        }
    }
    __syncthreads();

    // ---- Phase 3: segmented max, contiguous b64 reads + packed u16 max
    const int nValid = (P - base < 256) ? (P - base) : 256;
    if (nValid <= 0) return;
    const unsigned n0 = sn01[0];
    const unsigned n1 = sn01[1];
    const unsigned bEnd = (unsigned)(base + nValid);
    const int wave = tid >> 6;
    const int ch   = tid & 63;
    const unsigned short* rowp = &shbt[ch * 260];

    for (unsigned n = n0 + (unsigned)wave; n <= n1; n += 4) {
        const unsigned s = offsets[n];
        const unsigned e = offsets[n + 1];
        int lo = (int)(s > (unsigned)base ? s : (unsigned)base) - base;
        int hi = (int)(e < bEnd ? e : bEnd) - base;
        if (hi <= lo) continue;   // empty node inside range: leave 0
        u16x2 accv = {0, 0};
        unsigned short accs = 0;
        for (int r = lo & ~3; r < hi; r += 4) {
            uint2 d = *reinterpret_cast<const uint2*>(rowp + r);
            if (r >= lo && r + 4 <= hi) {
                u16x2 a = __builtin_bit_cast(u16x2, d.x);
                u16x2 b = __builtin_bit_cast(u16x2, d.y);
                accv = __builtin_elementwise_max(accv, __builtin_elementwise_max(a, b));
            } else {
                unsigned short v0 = (unsigned short)(d.x & 0xFFFFu);
                unsigned short v1 = (unsigned short)(d.x >> 16);
                unsigned short v2 = (unsigned short)(d.y & 0xFFFFu);
                unsigned short v3 = (unsigned short)(d.y >> 16);
                if (r     >= lo && r     < hi && v0 > accs) accs = v0;
                if (r + 1 >= lo && r + 1 < hi && v1 > accs) accs = v1;
                if (r + 2 >= lo && r + 2 < hi && v2 > accs) accs = v2;
                if (r + 3 >= lo && r + 3 < hi && v3 > accs) accs = v3;
            }
        }
        unsigned short k = accv.x > accv.y ? accv.x : accv.y;
        if (accs > k) k = accs;
        const unsigned key = ((unsigned)k) << 16;
        unsigned* dst = &segord[(size_t)n * 64 + ch];
        if (s >= (unsigned)base && e <= bEnd) *dst = key;   // sole writer
        else atomicMax(dst, key);                            // boundary node
    }
}

// ---------------------------------------------------------------------------
// K5: MLP2 fully in MFMA with split-bf16. Grid 512 (measured better than
// 2048 in R5 A/B: +13 µs at 2048).
// ---------------------------------------------------------------------------
__global__ __launch_bounds__(256) void mlp2_mfma_kernel(
    const unsigned* __restrict__ segord,
    const unsigned short* __restrict__ W3th, const unsigned short* __restrict__ W3tl,
    const unsigned short* __restrict__ W4th, const unsigned short* __restrict__ W4tl,
    const float* __restrict__ b3, const float* __restrict__ g2,
    const float* __restrict__ be2, const float* __restrict__ b4,
    float* __restrict__ out, int N)
{
    __shared__ __align__(16) unsigned short sa2[32 * 72];
    __shared__ __align__(16) float st[32 * 132];
    __shared__ __align__(16) unsigned short suh[32 * 136];
    __shared__ __align__(16) unsigned short sul[32 * 136];
    __shared__ float2 sred[32][8];
    __shared__ float sg2[128], sbe2[128];

    const int tid  = threadIdx.x;
    const int wv   = tid >> 6;
    const int lane = tid & 63;
    const int m    = lane & 15;
    const int quad = lane >> 4;

    if (tid < 128) { sg2[tid] = g2[tid]; sbe2[tid] = be2[tid]; }

    bf16x8 fw3h[2][2], fw3l[2][2];
    bf16x8 fw4h[2][4], fw4l[2][4];
    float bias3[2], bias4[2];
#pragma unroll
    for (int nti = 0; nti < 2; nti++) {
        const int nrow = (wv * 2 + nti) * 16 + m;
        bias3[nti] = b3[nrow];
        bias4[nti] = b4[nrow];
#pragma unroll
        for (int ks = 0; ks < 2; ks++) {
            fw3h[nti][ks] = *reinterpret_cast<const bf16x8*>(&W3th[nrow * 64 + ks * 32 + quad * 8]);
            fw3l[nti][ks] = *reinterpret_cast<const bf16x8*>(&W3tl[nrow * 64 + ks * 32 + quad * 8]);
        }
#pragma unroll
        for (int ks = 0; ks < 4; ks++) {
            fw4h[nti][ks] = *reinterpret_cast<const bf16x8*>(&W4th[nrow * 128 + ks * 32 + quad * 8]);
            fw4l[nti][ks] = *reinterpret_cast<const bf16x8*>(&W4tl[nrow * 128 + ks * 32 + quad * 8]);
        }
    }
    __syncthreads();

    for (int nb = blockIdx.x * 32; nb < N; nb += gridDim.x * 32) {
        {
            const int node = tid >> 3;
            const int k8   = (tid & 7) * 8;
            const uint4* sp = (const uint4*)&segord[(size_t)(nb + node) * 64 + k8];
            uint4 q0 = sp[0], q1 = sp[1];
            bf16x8 v;
            v[0] = (short)f2bf(decseg(q0.x));
            v[1] = (short)f2bf(decseg(q0.y));
            v[2] = (short)f2bf(decseg(q0.z));
            v[3] = (short)f2bf(decseg(q0.w));
            v[4] = (short)f2bf(decseg(q1.x));
            v[5] = (short)f2bf(decseg(q1.y));
            v[6] = (short)f2bf(decseg(q1.z));
            v[7] = (short)f2bf(decseg(q1.w));
            *reinterpret_cast<bf16x8*>(&sa2[node * 72 + k8]) = v;
        }
        __syncthreads();

#pragma unroll
        for (int mt = 0; mt < 2; mt++) {
            bf16x8 a0 = *reinterpret_cast<const bf16x8*>(&sa2[(mt * 16 + m) * 72 + quad * 8]);
            bf16x8 a1 = *reinterpret_cast<const bf16x8*>(&sa2[(mt * 16 + m) * 72 + 32 + quad * 8]);
#pragma unroll
            for (int nti = 0; nti < 2; nti++) {
                f32x4 acc = {bias3[nti], bias3[nti], bias3[nti], bias3[nti]};
                acc = __builtin_amdgcn_mfma_f32_16x16x32_bf16(a0, fw3h[nti][0], acc, 0, 0, 0);
                acc = __builtin_amdgcn_mfma_f32_16x16x32_bf16(a1, fw3h[nti][1], acc, 0, 0, 0);
                acc = __builtin_amdgcn_mfma_f32_16x16x32_bf16(a0, fw3l[nti][0], acc, 0, 0, 0);
                acc = __builtin_amdgcn_mfma_f32_16x16x32_bf16(a1, fw3l[nti][1], acc, 0, 0, 0);
#pragma unroll
                for (int r = 0; r < 4; r++)
                    st[(mt * 16 + quad * 4 + r) * 132 + (wv * 2 + nti) * 16 + m] = acc[r];
            }
        }
        __syncthreads();

        {
            const int node = tid >> 3;
            const int seg  = tid & 7;
            const float4* rp = (const float4*)&st[node * 132 + seg * 16];
            float4 v0 = rp[0], v1 = rp[1], v2 = rp[2], v3 = rp[3];
            float s1 = v0.x + v0.y + v0.z + v0.w + v1.x + v1.y + v1.z + v1.w
                     + v2.x + v2.y + v2.z + v2.w + v3.x + v3.y + v3.z + v3.w;
            float s2 = 0.f;
            s2 = fmaf(v0.x, v0.x, s2); s2 = fmaf(v0.y, v0.y, s2); s2 = fmaf(v0.z, v0.z, s2); s2 = fmaf(v0.w, v0.w, s2);
            s2 = fmaf(v1.x, v1.x, s2); s2 = fmaf(v1.y, v1.y, s2); s2 = fmaf(v1.z, v1.z, s2); s2 = fmaf(v1.w, v1.w, s2);
            s2 = fmaf(v2.x, v2.x, s2); s2 = fmaf(v2.y, v2.y, s2); s2 = fmaf(v2.z, v2.z, s2); s2 = fmaf(v2.w, v2.w, s2);
            s2 = fmaf(v3.x, v3.x, s2); s2 = fmaf(v3.y, v3.y, s2); s2 = fmaf(v3.z, v3.z, s2); s2 = fmaf(v3.w, v3.w, s2);
            sred[node][seg] = make_float2(s1, s2);
            __syncthreads();

            float t1 = 0.f, t2 = 0.f;
#pragma unroll
            for (int i = 0; i < 8; i++) { float2 r = sred[node][i]; t1 += r.x; t2 += r.y; }
            const float mu  = t1 * (1.f / 128.f);
            float var = t2 * (1.f / 128.f) - mu * mu;
            var = var > 0.f ? var : 0.f;
            const float rsd = rsqrtf(var + EPS_LN);

            float tv[16] = {v0.x, v0.y, v0.z, v0.w, v1.x, v1.y, v1.z, v1.w,
                            v2.x, v2.y, v2.z, v2.w, v3.x, v3.y, v3.z, v3.w};
            bf16x8 vh[2], vl[2];
#pragma unroll
            for (int i = 0; i < 16; i++) {
                const int j = seg * 16 + i;
                float u = fmaf((tv[i] - mu) * rsd, sg2[j], sbe2[j]);
                u = u > 0.f ? u : 0.f;
                unsigned short uh = f2bf(u);
                unsigned short ul = f2bf(u - bf2f(uh));
                vh[i >> 3][i & 7] = (short)uh;
                vl[i >> 3][i & 7] = (short)ul;
            }
            *reinterpret_cast<bf16x8*>(&suh[node * 136 + seg * 16])     = vh[0];
            *reinterpret_cast<bf16x8*>(&suh[node * 136 + seg * 16 + 8]) = vh[1];
            *reinterpret_cast<bf16x8*>(&sul[node * 136 + seg * 16])     = vl[0];
            *reinterpret_cast<bf16x8*>(&sul[node * 136 + seg * 16 + 8]) = vl[1];
        }
        __syncthreads();

#pragma unroll
        for (int mt = 0; mt < 2; mt++) {
            bf16x8 ah[4], al[4];
#pragma unroll
            for (int ks = 0; ks < 4; ks++) {
                ah[ks] = *reinterpret_cast<const bf16x8*>(&suh[(mt * 16 + m) * 136 + ks * 32 + quad * 8]);
                al[ks] = *reinterpret_cast<const bf16x8*>(&sul[(mt * 16 + m) * 136 + ks * 32 + quad * 8]);
            }
#pragma unroll
            for (int nti = 0; nti < 2; nti++) {
                f32x4 acc = {bias4[nti], bias4[nti], bias4[nti], bias4[nti]};
#pragma unroll
                for (int ks = 0; ks < 4; ks++) {
                    acc = __builtin_amdgcn_mfma_f32_16x16x32_bf16(ah[ks], fw4h[nti][ks], acc, 0, 0, 0);
                    acc = __builtin_amdgcn_mfma_f32_16x16x32_bf16(al[ks], fw4h[nti][ks], acc, 0, 0, 0);
                    acc = __builtin_amdgcn_mfma_f32_16x16x32_bf16(ah[ks], fw4l[nti][ks], acc, 0, 0, 0);
                }
#pragma unroll
                for (int r = 0; r < 4; r++) {
                    const int node = nb + mt * 16 + quad * 4 + r;
                    if (node < N)
                        out[(size_t)node * 128 + (wv * 2 + nti) * 16 + m] = acc[r];
                }
            }
        }
        __syncthreads();
    }
}

extern "C" void kernel_launch(void* const* d_in, const int* in_sizes, int n_in,
                              void* d_out, int out_size, void* d_ws, size_t ws_size,
                              hipStream_t stream) {
    const float* x    = (const float*)d_in[0];
    const int*   bidx = (const int*)d_in[1];
    const float* W1  = (const float*)d_in[3];
    const float* b1  = (const float*)d_in[4];
    const float* g1  = (const float*)d_in[5];
    const float* be1 = (const float*)d_in[6];
    const float* W2  = (const float*)d_in[7];
    const float* b2  = (const float*)d_in[8];
    const float* W3  = (const float*)d_in[9];
    const float* b3  = (const float*)d_in[10];
    const float* g2  = (const float*)d_in[11];
    const float* be2 = (const float*)d_in[12];
    const float* W4  = (const float*)d_in[13];
    const float* b4  = (const float*)d_in[14];

    const int P = in_sizes[0] / 3;
    const int N = out_size / 128;
    const int nparts = (N + 31) >> 5;          // <= 2048
    const int nblk   = (P + 4095) / 4096;      // <= 512

    uintptr_t w = (uintptr_t)d_ws;
    auto align = [](uintptr_t v) { return (v + 255) & ~(uintptr_t)255; };
    unsigned* blockHist = (unsigned*)align(w);     w = (uintptr_t)(blockHist + (size_t)nblk * 2048);
    unsigned* binTotal  = (unsigned*)align(w);     w = (uintptr_t)(binTotal  + 2048);
    unsigned* partBase  = (unsigned*)align(w);     w = (uintptr_t)(partBase  + 2049);
    unsigned* offsets   = (unsigned*)align(w);     w = (uintptr_t)(offsets   + N + 1);
    float4*   xb        = (float4*)align(w);       w = (uintptr_t)(xb        + P);
    unsigned* segord    = (unsigned*)align(w);     w = (uintptr_t)(segord    + (size_t)N * 64);
    float*    pW1e      = (float*)align(w);        w = (uintptr_t)(pW1e      + 256);
    float*    pGB       = (float*)align(w);        w = (uintptr_t)(pGB       + 128);
    float*    pSG       = (float*)align(w);        w = (uintptr_t)(pSG       + 16);
    unsigned short* pW2t = (unsigned short*)align(w); w = (uintptr_t)(pW2t + 64 * 72);
    unsigned short* W3th = (unsigned short*)align(w); w = (uintptr_t)(W3th + 128 * 64);
    unsigned short* W3tl = (unsigned short*)align(w); w = (uintptr_t)(W3tl + 128 * 64);
    unsigned short* W4th = (unsigned short*)align(w); w = (uintptr_t)(W4th + 128 * 128);
    unsigned short* W4tl = (unsigned short*)align(w); w = (uintptr_t)(W4tl + 128 * 128);

    hipMemsetAsync(segord, 0, (size_t)N * 64 * sizeof(unsigned), stream);

    prep_kernel<<<1, 256, 0, stream>>>(W1, b1, g1, be1, W2, W3, W4,
                                       pW1e, pGB, pSG, pW2t, W3th, W3tl, W4th, W4tl);

    s1_count<<<nblk, 256, 0, stream>>>(bidx, blockHist, P);
    s2a_total<<<nparts, 256, 0, stream>>>(blockHist, binTotal, nblk);
    s2b_scan<<<1, 1024, 0, stream>>>(binTotal, partBase, nparts, P);
    s2c_cursor<<<nparts, 256, 0, stream>>>(blockHist, partBase, nblk);
    s3_scatter<<<nblk, 256, 0, stream>>>(bidx, x, blockHist, xb, P);
    s4_csr<<<nparts, 256, 0, stream>>>(partBase, offsets, xb, N);

    fused_mlp1_pool_kernel<<<(P + 255) / 256, 256, 0, stream>>>(
        xb, offsets, pW1e, pGB, pSG, pW2t, b2, segord, P);

    mlp2_mfma_kernel<<<512, 256, 0, stream>>>(
        segord, W3th, W3tl, W4th, W4tl, b3, g2, be2, b4, (float*)d_out, N);
}

// Round 8
// 335.150 us; speedup vs baseline: 1.8797x; 1.0007x over previous
//
#include <hip/hip_runtime.h>
#include <hip/hip_bf16.h>
#include <math.h>

#define EPS_LN 1e-5f

typedef __attribute__((ext_vector_type(8))) short bf16x8;
typedef __attribute__((ext_vector_type(4))) float f32x4;
typedef __attribute__((ext_vector_type(2))) unsigned short u16x2;
typedef __attribute__((ext_vector_type(4))) unsigned int u32x4;

__device__ __forceinline__ unsigned short f2bf(float f) {
    __hip_bfloat16 h = __float2bfloat16(f);
    return *reinterpret_cast<unsigned short*>(&h);
}
__device__ __forceinline__ float bf2f(unsigned short u) {
    return __uint_as_float(((unsigned)u) << 16);
}
// monotone 16-bit key of a bf16 pattern; 0 is below all real values
__device__ __forceinline__ unsigned short ok16(float f) {
    unsigned short t = f2bf(f);
    unsigned short mask = (unsigned short)(((short)t) >> 15);
    return (unsigned short)(t ^ (unsigned short)(mask | 0x8000u));
}
// decode segord entry (key16<<16; 0 == empty -> 0.0)
__device__ __forceinline__ float decseg(unsigned o) {
    if (o == 0u) return 0.f;
    unsigned k = o >> 16;
    unsigned h = (k & 0x8000u) ? (k & 0x7FFFu) : (~k & 0xFFFFu);
    return bf2f((unsigned short)h);
}

// ---------------------------------------------------------------------------
// K0: prep — pack params once per call.
// ---------------------------------------------------------------------------
__global__ __launch_bounds__(256) void prep_kernel(
    const float* __restrict__ W1, const float* __restrict__ b1,
    const float* __restrict__ g1, const float* __restrict__ be1,
    const float* __restrict__ W2,
    const float* __restrict__ W3, const float* __restrict__ W4,
    float* __restrict__ pW1e, float* __restrict__ pGB, float* __restrict__ pSG,
    unsigned short* __restrict__ pW2t,
    unsigned short* __restrict__ W3th, unsigned short* __restrict__ W3tl,
    unsigned short* __restrict__ W4th, unsigned short* __restrict__ W4tl)
{
    const int tid = threadIdx.x;
    if (tid < 64) {
        pW1e[4 * tid + 0] = W1[tid];
        pW1e[4 * tid + 1] = W1[64 + tid];
        pW1e[4 * tid + 2] = W1[128 + tid];
        pW1e[4 * tid + 3] = b1[tid];
        pGB[2 * tid + 0] = g1[tid];
        pGB[2 * tid + 1] = be1[tid];
    }
    if (tid >= 64 && tid < 78) {
        const int t = tid - 64;
        auto wcomp = [&](int k, int i) -> float {
            return (i < 3) ? W1[i * 64 + k] : b1[k];
        };
        if (t < 4) {
            float s = 0.f;
            for (int k = 0; k < 64; k++) s += wcomp(k, t);
            pSG[t] = s;
        } else {
            const int pi[10] = {0,0,0,0,1,1,1,2,2,3};
            const int pj[10] = {0,1,2,3,1,2,3,2,3,3};
            int p = t - 4;
            float s = 0.f;
            for (int k = 0; k < 64; k++) s += wcomp(k, pi[p]) * wcomp(k, pj[p]);
            pSG[4 + p] = s;
        }
    }
    for (int i = tid; i < 4096; i += 256) {
        int k = i >> 6, n = i & 63;
        pW2t[n * 72 + k] = f2bf(W2[i]);
    }
    for (int i = tid; i < 64 * 8; i += 256) {
        int n = i >> 3, k = 64 + (i & 7);
        pW2t[n * 72 + k] = 0;
    }
    for (int i = tid; i < 8192; i += 256) {
        int k = i >> 7, n = i & 127;
        float w = W3[k * 128 + n];
        unsigned short h = f2bf(w);
        W3th[n * 64 + k] = h;
        W3tl[n * 64 + k] = f2bf(w - bf2f(h));
    }
    for (int i = tid; i < 16384; i += 256) {
        int k = i >> 7, n = i & 127;
        float w = W4[k * 128 + n];
        unsigned short h = f2bf(w);
        W4th[n * 128 + k] = h;
        W4tl[n * 128 + k] = f2bf(w - bf2f(h));
    }
}

// ---------------------------------------------------------------------------
// Sort stage 1: per-block LDS hist over 2048 partitions (node>>5).
// NO global atomics.
// ---------------------------------------------------------------------------
__global__ __launch_bounds__(256) void s1_count(const int* __restrict__ bidx,
                                                unsigned* __restrict__ blockHist, int P) {
    __shared__ unsigned hist[2048];
    const int tid = threadIdx.x;
    for (int i = tid; i < 2048; i += 256) hist[i] = 0;
    __syncthreads();
    const int base = blockIdx.x * 4096;
#pragma unroll
    for (int j = 0; j < 4; j++) {
        const int p0 = base + j * 1024 + tid * 4;
        if (p0 + 3 < P) {
            int4 n4 = *(const int4*)(bidx + p0);
            atomicAdd(&hist[((unsigned)n4.x) >> 5], 1u);
            atomicAdd(&hist[((unsigned)n4.y) >> 5], 1u);
            atomicAdd(&hist[((unsigned)n4.z) >> 5], 1u);
            atomicAdd(&hist[((unsigned)n4.w) >> 5], 1u);
        } else {
            for (int p = p0; p < P && p < p0 + 4; p++)
                atomicAdd(&hist[((unsigned)bidx[p]) >> 5], 1u);
        }
    }
    __syncthreads();
    unsigned* dst = blockHist + (size_t)blockIdx.x * 2048;
    for (int i = tid; i < 2048; i += 256) dst[i] = hist[i];
}

// ---------------------------------------------------------------------------
// Sort stage 2ac (FUSED s2a+s2c): ONE column pass per bin — read the bin's
// per-block counts once, write back the per-block EXCLUSIVE scan (no
// partBase; s3 adds it at cursor-load), and emit binTotal[bin].
// Old pipeline did two column-major passes (s2a read + s2c read/write);
// column stride is 8 KB so each 4-B read drags a 64-B line (~67 MB
// effective per pass). This halves that traffic.
// ---------------------------------------------------------------------------
__global__ __launch_bounds__(256) void s2ac_scan(unsigned* __restrict__ blockHist,
                                                 unsigned* __restrict__ binTotal,
                                                 int nblk) {
    __shared__ unsigned wt0[4], wb0[4], wt1[4], wb1[4], tot0s;
    const int bin = blockIdx.x;
    const int tid = threadIdx.x;
    const int lane = tid & 63;
    const unsigned c0 = (tid < nblk) ? blockHist[(size_t)tid * 2048 + bin] : 0u;
    const unsigned c1 = (tid + 256 < nblk) ? blockHist[(size_t)(tid + 256) * 2048 + bin] : 0u;

    unsigned v0 = c0;
    for (int off = 1; off < 64; off <<= 1) {
        unsigned u = __shfl_up(v0, off);
        if (lane >= off) v0 += u;
    }
    if (lane == 63) wt0[tid >> 6] = v0;
    unsigned v1 = c1;
    for (int off = 1; off < 64; off <<= 1) {
        unsigned u = __shfl_up(v1, off);
        if (lane >= off) v1 += u;
    }
    if (lane == 63) wt1[tid >> 6] = v1;
    __syncthreads();
    if (tid == 0) {
        unsigned a = 0;
        for (int i = 0; i < 4; i++) { unsigned tmp = wt0[i]; wb0[i] = a; a += tmp; }
        tot0s = a;
        unsigned b = 0;
        for (int i = 0; i < 4; i++) { unsigned tmp = wt1[i]; wb1[i] = b; b += tmp; }
        binTotal[bin] = a + b;   // total over all blocks
    }
    __syncthreads();
    const unsigned e0 = wb0[tid >> 6] + (v0 - c0);
    const unsigned e1 = tot0s + wb1[tid >> 6] + (v1 - c1);
    if (tid < nblk) blockHist[(size_t)tid * 2048 + bin] = e0;
    if (tid + 256 < nblk) blockHist[(size_t)(tid + 256) * 2048 + bin] = e1;
}

// ---------------------------------------------------------------------------
// Sort stage 2b: exclusive scan of binTotal -> partBase[nparts+1]. 1 block.
// ---------------------------------------------------------------------------
__global__ __launch_bounds__(1024) void s2b_scan(const unsigned* __restrict__ binTotal,
                                                 unsigned* __restrict__ partBase,
                                                 int nparts, int P) {
    __shared__ unsigned wtot[16];
    const int t = threadIdx.x;
    const unsigned c0 = (2 * t < nparts) ? binTotal[2 * t] : 0u;
    const unsigned c1 = (2 * t + 1 < nparts) ? binTotal[2 * t + 1] : 0u;
    const unsigned s = c0 + c1;
    unsigned v = s;
    const int lane = t & 63;
    for (int off = 1; off < 64; off <<= 1) {
        unsigned u = __shfl_up(v, off);
        if (lane >= off) v += u;
    }
    if (lane == 63) wtot[t >> 6] = v;
    __syncthreads();
    if (t == 0) {
        unsigned a = 0;
        for (int w = 0; w < 16; w++) { unsigned tmp = wtot[w]; wtot[w] = a; a += tmp; }
    }
    __syncthreads();
    const unsigned excl = wtot[t >> 6] + (v - s);
    if (2 * t < nparts) partBase[2 * t] = excl;
    if (2 * t + 1 < nparts) partBase[2 * t + 1] = excl + c0;
    if (t == 0) partBase[nparts] = (unsigned)P;
}

// ---------------------------------------------------------------------------
// Sort stage 3: scatter (x,node) float4 into partition-grouped xb using
// deterministic cursors (LDS-local atomics only). Cursor = per-block
// exclusive (from s2ac, in blockHist) + partBase[bin] added at load.
// ---------------------------------------------------------------------------
__global__ __launch_bounds__(256) void s3_scatter(const int* __restrict__ bidx,
                                                  const float* __restrict__ x,
                                                  const unsigned* __restrict__ blockCursor,
                                                  const unsigned* __restrict__ partBase,
                                                  float4* __restrict__ xb, int P) {
    __shared__ unsigned cur[2048];
    const int tid = threadIdx.x;
    const unsigned* src = blockCursor + (size_t)blockIdx.x * 2048;
    for (int i = tid; i < 2048; i += 256) cur[i] = src[i] + partBase[i];
    __syncthreads();
    const int base = blockIdx.x * 4096;
#pragma unroll
    for (int j = 0; j < 4; j++) {
        const int p0 = base + j * 1024 + tid * 4;
        if (p0 + 3 < P) {
            int4 n4 = *(const int4*)(bidx + p0);
            const float4* xv = (const float4*)(x + 3 * (size_t)p0);
            float4 a = xv[0], b = xv[1], c = xv[2];
            const float xs[12] = {a.x, a.y, a.z, a.w, b.x, b.y, b.z, b.w,
                                  c.x, c.y, c.z, c.w};
            const unsigned nn[4] = {(unsigned)n4.x, (unsigned)n4.y,
                                    (unsigned)n4.z, (unsigned)n4.w};
#pragma unroll
            for (int u = 0; u < 4; u++) {
                const unsigned dst = atomicAdd(&cur[nn[u] >> 5], 1u);
                xb[dst] = make_float4(xs[3 * u], xs[3 * u + 1], xs[3 * u + 2],
                                      __uint_as_float(nn[u]));
            }
        } else {
            for (int u = 0; u < 4; u++) {
                const int p = p0 + u;
                if (p < P) {
                    const unsigned n = (unsigned)bidx[p];
                    const unsigned dst = atomicAdd(&cur[n >> 5], 1u);
                    xb[dst] = make_float4(x[3 * p], x[3 * p + 1], x[3 * p + 2],
                                          __uint_as_float(n));
                }
            }
        }
    }
}

// ---------------------------------------------------------------------------
// Sort stage 4: per-partition CSR + node-sort. One block per partition.
// ---------------------------------------------------------------------------
__global__ __launch_bounds__(256) void s4_csr(const unsigned* __restrict__ partBase,
                                              unsigned* __restrict__ offsets,
                                              float4* __restrict__ xb, int N) {
    __shared__ float4 stage[1600];
    __shared__ unsigned hist[32], cur[32];
    const int tid = threadIdx.x;
    const int p = blockIdx.x;
    const unsigned start = partBase[p], end = partBase[p + 1];
    unsigned cnt = end - start;
    if (cnt > 1600u) cnt = 1600u;
    if (tid < 32) hist[tid] = 0;
    __syncthreads();
    for (unsigned k = tid; k < cnt; k += 256) {
        float4 r = xb[start + k];
        stage[k] = r;
        atomicAdd(&hist[__float_as_uint(r.w) & 31u], 1u);
    }
    __syncthreads();
    if (tid < 64) {
        const unsigned c = (tid < 32) ? hist[tid] : 0u;
        unsigned v = c;
        for (int off = 1; off < 32; off <<= 1) {
            unsigned u = __shfl_up(v, off);
            if (tid >= off) v += u;
        }
        if (tid < 32) {
            const unsigned excl = v - c;
            const int node = p * 32 + tid;
            if (node < N) offsets[node] = start + excl;
            cur[tid] = start + excl;
            if (node == N - 1) offsets[N] = start + excl + c;
        }
    }
    __syncthreads();
    for (unsigned k = tid; k < cnt; k += 256) {
        float4 r = stage[k];
        const unsigned dst = atomicAdd(&cur[__float_as_uint(r.w) & 31u], 1u);
        xb[dst] = r;
    }
}

// ---------------------------------------------------------------------------
// K4: fused MLP1 + chunk-segmented max pool — EXACT Round-5/7 measured-good
// version (92.6 µs, FETCH 17 MB / WRITE 18 MB, VALUBusy 58%). FROZEN.
// ---------------------------------------------------------------------------
__global__ __launch_bounds__(256, 3) void fused_mlp1_pool_kernel(
    const float4* __restrict__ xb, const unsigned* __restrict__ offsets,
    const float* __restrict__ pW1e, const float* __restrict__ pGB,
    const float* __restrict__ pSG, const unsigned short* __restrict__ pW2t,
    const float* __restrict__ b2,
    unsigned* __restrict__ segord, int P)
{
    __shared__ __align__(16) unsigned short shbt[64 * 260];  // 33.3 KB, [ch][row]
    __shared__ unsigned sn01[2];

    const int tid  = threadIdx.x;
    const int wv   = tid >> 6;
    const int lane = tid & 63;
    const int m    = lane & 15;
    const int quad = lane >> 4;
    const int base = blockIdx.x * 256;
    const int pos  = base + tid;
    const bool valid = (pos < P);

    // ---- W2 B-fragments + bias: straight from global into registers
    bf16x8 bfrag[4][2];
    float bc[4];
#pragma unroll
    for (int nt = 0; nt < 4; nt++) {
        bc[nt] = b2[nt * 16 + m];
#pragma unroll
        for (int s = 0; s < 2; s++)
            bfrag[nt][s] = *reinterpret_cast<const bf16x8*>(
                &pW2t[(nt * 16 + m) * 72 + s * 32 + quad * 8]);
    }

    // ---- own row load + LN stats via Gram trick
    float x0 = 0.f, x1 = 0.f, x2 = 0.f;
    if (valid) {
        float4 v = xb[pos];
        x0 = v.x; x1 = v.y; x2 = v.z;
        unsigned node = __float_as_uint(v.w);
        if (tid == 0) sn01[0] = node;
        if (tid == 255 || pos == P - 1) sn01[1] = node;
    }

    float rs, r2;
    {
        const float S0 = pSG[0], S1 = pSG[1], S2 = pSG[2], S3 = pSG[3];
        const float g00 = pSG[4], g01 = pSG[5], g02 = pSG[6], g03 = pSG[7];
        const float g11 = pSG[8], g12 = pSG[9], g13 = pSG[10];
        const float g22 = pSG[11], g23 = pSG[12], g33 = pSG[13];

        const float mu = fmaf(S0, x0, fmaf(S1, x1, fmaf(S2, x2, S3))) * (1.f / 64.f);
        float q = g33;
        q = fmaf(g00, x0 * x0, q);
        q = fmaf(g11, x1 * x1, q);
        q = fmaf(g22, x2 * x2, q);
        float c = fmaf(g01, x1, fmaf(g02, x2, g03));
        q = fmaf(2.f * x0, c, q);
        q = fmaf(2.f * x1, fmaf(g12, x2, g13), q);
        q = fmaf(2.f * x2, g23, q);
        float var = q * (1.f / 64.f) - mu * mu;
        var = var > 0.f ? var : 0.f;
        rs = rsqrtf(var + EPS_LN);
        r2 = -mu * rs;
    }

    // ---- deliver x/stats of the 4 rows this lane serves (wave-local rows)
    float xr0[4], xr1[4], xr2[4], rsr[4], r2r[4];
#pragma unroll
    for (int rt = 0; rt < 4; rt++) {
        const int src = rt * 16 + m;
        xr0[rt] = __shfl(x0, src);
        xr1[rt] = __shfl(x1, src);
        xr2[rt] = __shfl(x2, src);
        rsr[rt] = __shfl(rs, src);
        r2r[rt] = __shfl(r2, src);
    }

    // ---- Phase 1: layer-1 + LN + ReLU, computed directly in A-frag layout.
    u32x4 afr[4][2];
    {
        const float4* pw = (const float4*)pW1e;
        const float2* pg = (const float2*)pGB;
#pragma unroll
        for (int s = 0; s < 2; s++) {
#pragma unroll
            for (int up = 0; up < 4; up++) {
                const int ch = s * 32 + quad * 8 + up * 2;
                const float4 wA = pw[ch], wB = pw[ch + 1];
                const float2 gA = pg[ch], gB = pg[ch + 1];
#pragma unroll
                for (int rt = 0; rt < 4; rt++) {
                    float y0 = fmaf(xr0[rt], wA.x, fmaf(xr1[rt], wA.y,
                               fmaf(xr2[rt], wA.z, wA.w)));
                    float y1 = fmaf(xr0[rt], wB.x, fmaf(xr1[rt], wB.y,
                               fmaf(xr2[rt], wB.z, wB.w)));
                    float a0 = fmaf(fmaf(y0, rsr[rt], r2r[rt]), gA.x, gA.y);
                    float a1 = fmaf(fmaf(y1, rsr[rt], r2r[rt]), gB.x, gB.y);
                    a0 = a0 > 0.f ? a0 : 0.f;
                    a1 = a1 > 0.f ? a1 : 0.f;
                    afr[rt][s][up] = (unsigned)f2bf(a0) | ((unsigned)f2bf(a1) << 16);
                }
            }
        }
    }

    // ---- Phase 2: h = a @ W2 + b2 via MFMA; transposed ordkey16 store
#pragma unroll
    for (int rt = 0; rt < 4; rt++) {
        const int orow = wv * 64 + rt * 16 + quad * 4;   // C rows this lane owns
        const bf16x8 af0 = __builtin_bit_cast(bf16x8, afr[rt][0]);
        const bf16x8 af1 = __builtin_bit_cast(bf16x8, afr[rt][1]);
#pragma unroll
        for (int nt = 0; nt < 4; nt++) {
            f32x4 acc = {bc[nt], bc[nt], bc[nt], bc[nt]};
            acc = __builtin_amdgcn_mfma_f32_16x16x32_bf16(af0, bfrag[nt][0], acc, 0, 0, 0);
            acc = __builtin_amdgcn_mfma_f32_16x16x32_bf16(af1, bfrag[nt][1], acc, 0, 0, 0);
            const int col = nt * 16 + m;
            uint2 pk;
            pk.x = (unsigned)ok16(acc[0]) | ((unsigned)ok16(acc[1]) << 16);
            pk.y = (unsigned)ok16(acc[2]) | ((unsigned)ok16(acc[3]) << 16);
            *reinterpret_cast<uint2*>(&shbt[col * 260 + orow]) = pk;
        }
    }
    __syncthreads();

    // ---- Phase 3: segmented max, contiguous b64 reads + packed u16 max
    const int nValid = (P - base < 256) ? (P - base) : 256;
    if (nValid <= 0) return;
    const unsigned n0 = sn01[0];
    const unsigned n1 = sn01[1];
    const unsigned bEnd = (unsigned)(base + nValid);
    const int wave = tid >> 6;
    const int ch   = tid & 63;
    const unsigned short* rowp = &shbt[ch * 260];

    for (unsigned n = n0 + (unsigned)wave; n <= n1; n += 4) {
        const unsigned s = offsets[n];
        const unsigned e = offsets[n + 1];
        int lo = (int)(s > (unsigned)base ? s : (unsigned)base) - base;
        int hi = (int)(e < bEnd ? e : bEnd) - base;
        if (hi <= lo) continue;   // empty node inside range: leave 0
        u16x2 accv = {0, 0};
        unsigned short accs = 0;
        for (int r = lo & ~3; r < hi; r += 4) {
            uint2 d = *reinterpret_cast<const uint2*>(rowp + r);
            if (r >= lo && r + 4 <= hi) {
                u16x2 a = __builtin_bit_cast(u16x2, d.x);
                u16x2 b = __builtin_bit_cast(u16x2, d.y);
                accv = __builtin_elementwise_max(accv, __builtin_elementwise_max(a, b));
            } else {
                unsigned short v0 = (unsigned short)(d.x & 0xFFFFu);
                unsigned short v1 = (unsigned short)(d.x >> 16);
                unsigned short v2 = (unsigned short)(d.y & 0xFFFFu);
                unsigned short v3 = (unsigned short)(d.y >> 16);
                if (r     >= lo && r     < hi && v0 > accs) accs = v0;
                if (r + 1 >= lo && r + 1 < hi && v1 > accs) accs = v1;
                if (r + 2 >= lo && r + 2 < hi && v2 > accs) accs = v2;
                if (r + 3 >= lo && r + 3 < hi && v3 > accs) accs = v3;
            }
        }
        unsigned short k = accv.x > accv.y ? accv.x : accv.y;
        if (accs > k) k = accs;
        const unsigned key = ((unsigned)k) << 16;
        unsigned* dst = &segord[(size_t)n * 64 + ch];
        if (s >= (unsigned)base && e <= bEnd) *dst = key;   // sole writer
        else atomicMax(dst, key);                            // boundary node
    }
}

// ---------------------------------------------------------------------------
// K5: MLP2 fully in MFMA with split-bf16. Grid 512 (measured better than
// 2048 in R5 A/B: +13 µs at 2048).
// ---------------------------------------------------------------------------
__global__ __launch_bounds__(256) void mlp2_mfma_kernel(
    const unsigned* __restrict__ segord,
    const unsigned short* __restrict__ W3th, const unsigned short* __restrict__ W3tl,
    const unsigned short* __restrict__ W4th, const unsigned short* __restrict__ W4tl,
    const float* __restrict__ b3, const float* __restrict__ g2,
    const float* __restrict__ be2, const float* __restrict__ b4,
    float* __restrict__ out, int N)
{
    __shared__ __align__(16) unsigned short sa2[32 * 72];
    __shared__ __align__(16) float st[32 * 132];
    __shared__ __align__(16) unsigned short suh[32 * 136];
    __shared__ __align__(16) unsigned short sul[32 * 136];
    __shared__ float2 sred[32][8];
    __shared__ float sg2[128], sbe2[128];

    const int tid  = threadIdx.x;
    const int wv   = tid >> 6;
    const int lane = tid & 63;
    const int m    = lane & 15;
    const int quad = lane >> 4;

    if (tid < 128) { sg2[tid] = g2[tid]; sbe2[tid] = be2[tid]; }

    bf16x8 fw3h[2][2], fw3l[2][2];
    bf16x8 fw4h[2][4], fw4l[2][4];
    float bias3[2], bias4[2];
#pragma unroll
    for (int nti = 0; nti < 2; nti++) {
        const int nrow = (wv * 2 + nti) * 16 + m;
        bias3[nti] = b3[nrow];
        bias4[nti] = b4[nrow];
#pragma unroll
        for (int ks = 0; ks < 2; ks++) {
            fw3h[nti][ks] = *reinterpret_cast<const bf16x8*>(&W3th[nrow * 64 + ks * 32 + quad * 8]);
            fw3l[nti][ks] = *reinterpret_cast<const bf16x8*>(&W3tl[nrow * 64 + ks * 32 + quad * 8]);
        }
#pragma unroll
        for (int ks = 0; ks < 4; ks++) {
            fw4h[nti][ks] = *reinterpret_cast<const bf16x8*>(&W4th[nrow * 128 + ks * 32 + quad * 8]);
            fw4l[nti][ks] = *reinterpret_cast<const bf16x8*>(&W4tl[nrow * 128 + ks * 32 + quad * 8]);
        }
    }
    __syncthreads();

    for (int nb = blockIdx.x * 32; nb < N; nb += gridDim.x * 32) {
        {
            const int node = tid >> 3;
            const int k8   = (tid & 7) * 8;
            const uint4* sp = (const uint4*)&segord[(size_t)(nb + node) * 64 + k8];
            uint4 q0 = sp[0], q1 = sp[1];
            bf16x8 v;
            v[0] = (short)f2bf(decseg(q0.x));
            v[1] = (short)f2bf(decseg(q0.y));
            v[2] = (short)f2bf(decseg(q0.z));
            v[3] = (short)f2bf(decseg(q0.w));
            v[4] = (short)f2bf(decseg(q1.x));
            v[5] = (short)f2bf(decseg(q1.y));
            v[6] = (short)f2bf(decseg(q1.z));
            v[7] = (short)f2bf(decseg(q1.w));
            *reinterpret_cast<bf16x8*>(&sa2[node * 72 + k8]) = v;
        }
        __syncthreads();

#pragma unroll
        for (int mt = 0; mt < 2; mt++) {
            bf16x8 a0 = *reinterpret_cast<const bf16x8*>(&sa2[(mt * 16 + m) * 72 + quad * 8]);
            bf16x8 a1 = *reinterpret_cast<const bf16x8*>(&sa2[(mt * 16 + m) * 72 + 32 + quad * 8]);
#pragma unroll
            for (int nti = 0; nti < 2; nti++) {
                f32x4 acc = {bias3[nti], bias3[nti], bias3[nti], bias3[nti]};
                acc = __builtin_amdgcn_mfma_f32_16x16x32_bf16(a0, fw3h[nti][0], acc, 0, 0, 0);
                acc = __builtin_amdgcn_mfma_f32_16x16x32_bf16(a1, fw3h[nti][1], acc, 0, 0, 0);
                acc = __builtin_amdgcn_mfma_f32_16x16x32_bf16(a0, fw3l[nti][0], acc, 0, 0, 0);
                acc = __builtin_amdgcn_mfma_f32_16x16x32_bf16(a1, fw3l[nti][1], acc, 0, 0, 0);
#pragma unroll
                for (int r = 0; r < 4; r++)
                    st[(mt * 16 + quad * 4 + r) * 132 + (wv * 2 + nti) * 16 + m] = acc[r];
            }
        }
        __syncthreads();

        {
            const int node = tid >> 3;
            const int seg  = tid & 7;
            const float4* rp = (const float4*)&st[node * 132 + seg * 16];
            float4 v0 = rp[0], v1 = rp[1], v2 = rp[2], v3 = rp[3];
            float s1 = v0.x + v0.y + v0.z + v0.w + v1.x + v1.y + v1.z + v1.w
                     + v2.x + v2.y + v2.z + v2.w + v3.x + v3.y + v3.z + v3.w;
            float s2 = 0.f;
            s2 = fmaf(v0.x, v0.x, s2); s2 = fmaf(v0.y, v0.y, s2); s2 = fmaf(v0.z, v0.z, s2); s2 = fmaf(v0.w, v0.w, s2);
            s2 = fmaf(v1.x, v1.x, s2); s2 = fmaf(v1.y, v1.y, s2); s2 = fmaf(v1.z, v1.z, s2); s2 = fmaf(v1.w, v1.w, s2);
            s2 = fmaf(v2.x, v2.x, s2); s2 = fmaf(v2.y, v2.y, s2); s2 = fmaf(v2.z, v2.z, s2); s2 = fmaf(v2.w, v2.w, s2);
            s2 = fmaf(v3.x, v3.x, s2); s2 = fmaf(v3.y, v3.y, s2); s2 = fmaf(v3.z, v3.z, s2); s2 = fmaf(v3.w, v3.w, s2);
            sred[node][seg] = make_float2(s1, s2);
            __syncthreads();

            float t1 = 0.f, t2 = 0.f;
#pragma unroll
            for (int i = 0; i < 8; i++) { float2 r = sred[node][i]; t1 += r.x; t2 += r.y; }
            const float mu  = t1 * (1.f / 128.f);
            float var = t2 * (1.f / 128.f) - mu * mu;
            var = var > 0.f ? var : 0.f;
            const float rsd = rsqrtf(var + EPS_LN);

            float tv[16] = {v0.x, v0.y, v0.z, v0.w, v1.x, v1.y, v1.z, v1.w,
                            v2.x, v2.y, v2.z, v2.w, v3.x, v3.y, v3.z, v3.w};
            bf16x8 vh[2], vl[2];
#pragma unroll
            for (int i = 0; i < 16; i++) {
                const int j = seg * 16 + i;
                float u = fmaf((tv[i] - mu) * rsd, sg2[j], sbe2[j]);
                u = u > 0.f ? u : 0.f;
                unsigned short uh = f2bf(u);
                unsigned short ul = f2bf(u - bf2f(uh));
                vh[i >> 3][i & 7] = (short)uh;
                vl[i >> 3][i & 7] = (short)ul;
            }
            *reinterpret_cast<bf16x8*>(&suh[node * 136 + seg * 16])     = vh[0];
            *reinterpret_cast<bf16x8*>(&suh[node * 136 + seg * 16 + 8]) = vh[1];
            *reinterpret_cast<bf16x8*>(&sul[node * 136 + seg * 16])     = vl[0];
            *reinterpret_cast<bf16x8*>(&sul[node * 136 + seg * 16 + 8]) = vl[1];
        }
        __syncthreads();

#pragma unroll
        for (int mt = 0; mt < 2; mt++) {
            bf16x8 ah[4], al[4];
#pragma unroll
            for (int ks = 0; ks < 4; ks++) {
                ah[ks] = *reinterpret_cast<const bf16x8*>(&suh[(mt * 16 + m) * 136 + ks * 32 + quad * 8]);
                al[ks] = *reinterpret_cast<const bf16x8*>(&sul[(mt * 16 + m) * 136 + ks * 32 + quad * 8]);
            }
#pragma unroll
            for (int nti = 0; nti < 2; nti++) {
                f32x4 acc = {bias4[nti], bias4[nti], bias4[nti], bias4[nti]};
#pragma unroll
                for (int ks = 0; ks < 4; ks++) {
                    acc = __builtin_amdgcn_mfma_f32_16x16x32_bf16(ah[ks], fw4h[nti][ks], acc, 0, 0, 0);
                    acc = __builtin_amdgcn_mfma_f32_16x16x32_bf16(al[ks], fw4h[nti][ks], acc, 0, 0, 0);
                    acc = __builtin_amdgcn_mfma_f32_16x16x32_bf16(ah[ks], fw4l[nti][ks], acc, 0, 0, 0);
                }
#pragma unroll
                for (int r = 0; r < 4; r++) {
                    const int node = nb + mt * 16 + quad * 4 + r;
                    if (node < N)
                        out[(size_t)node * 128 + (wv * 2 + nti) * 16 + m] = acc[r];
                }
            }
        }
        __syncthreads();
    }
}

extern "C" void kernel_launch(void* const* d_in, const int* in_sizes, int n_in,
                              void* d_out, int out_size, void* d_ws, size_t ws_size,
                              hipStream_t stream) {
    const float* x    = (const float*)d_in[0];
    const int*   bidx = (const int*)d_in[1];
    const float* W1  = (const float*)d_in[3];
    const float* b1  = (const float*)d_in[4];
    const float* g1  = (const float*)d_in[5];
    const float* be1 = (const float*)d_in[6];
    const float* W2  = (const float*)d_in[7];
    const float* b2  = (const float*)d_in[8];
    const float* W3  = (const float*)d_in[9];
    const float* b3  = (const float*)d_in[10];
    const float* g2  = (const float*)d_in[11];
    const float* be2 = (const float*)d_in[12];
    const float* W4  = (const float*)d_in[13];
    const float* b4  = (const float*)d_in[14];

    const int P = in_sizes[0] / 3;
    const int N = out_size / 128;
    const int nparts = (N + 31) >> 5;          // <= 2048
    const int nblk   = (P + 4095) / 4096;      // <= 512

    uintptr_t w = (uintptr_t)d_ws;
    auto align = [](uintptr_t v) { return (v + 255) & ~(uintptr_t)255; };
    unsigned* blockHist = (unsigned*)align(w);     w = (uintptr_t)(blockHist + (size_t)nblk * 2048);
    unsigned* binTotal  = (unsigned*)align(w);     w = (uintptr_t)(binTotal  + 2048);
    unsigned* partBase  = (unsigned*)align(w);     w = (uintptr_t)(partBase  + 2049);
    unsigned* offsets   = (unsigned*)align(w);     w = (uintptr_t)(offsets   + N + 1);
    float4*   xb        = (float4*)align(w);       w = (uintptr_t)(xb        + P);
    unsigned* segord    = (unsigned*)align(w);     w = (uintptr_t)(segord    + (size_t)N * 64);
    float*    pW1e      = (float*)align(w);        w = (uintptr_t)(pW1e      + 256);
    float*    pGB       = (float*)align(w);        w = (uintptr_t)(pGB       + 128);
    float*    pSG       = (float*)align(w);        w = (uintptr_t)(pSG       + 16);
    unsigned short* pW2t = (unsigned short*)align(w); w = (uintptr_t)(pW2t + 64 * 72);
    unsigned short* W3th = (unsigned short*)align(w); w = (uintptr_t)(W3th + 128 * 64);
    unsigned short* W3tl = (unsigned short*)align(w); w = (uintptr_t)(W3tl + 128 * 64);
    unsigned short* W4th = (unsigned short*)align(w); w = (uintptr_t)(W4th + 128 * 128);
    unsigned short* W4tl = (unsigned short*)align(w); w = (uintptr_t)(W4tl + 128 * 128);

    hipMemsetAsync(segord, 0, (size_t)N * 64 * sizeof(unsigned), stream);

    prep_kernel<<<1, 256, 0, stream>>>(W1, b1, g1, be1, W2, W3, W4,
                                       pW1e, pGB, pSG, pW2t, W3th, W3tl, W4th, W4tl);

    s1_count<<<nblk, 256, 0, stream>>>(bidx, blockHist, P);
    s2ac_scan<<<nparts, 256, 0, stream>>>(blockHist, binTotal, nblk);
    s2b_scan<<<1, 1024, 0, stream>>>(binTotal, partBase, nparts, P);
    s3_scatter<<<nblk, 256, 0, stream>>>(bidx, x, blockHist, partBase, xb, P);
    s4_csr<<<nparts, 256, 0, stream>>>(partBase, offsets, xb, N);

    fused_mlp1_pool_kernel<<<(P + 255) / 256, 256, 0, stream>>>(
        xb, offsets, pW1e, pGB, pSG, pW2t, b2, segord, P);

    mlp2_mfma_kernel<<<512, 256, 0, stream>>>(
        segord, W3th, W3tl, W4th, W4tl, b3, g2, be2, b4, (float*)d_out, N);
}

// Round 9
// 328.358 us; speedup vs baseline: 1.9186x; 1.0207x over previous
//
#include <hip/hip_runtime.h>
#include <hip/hip_bf16.h>
#include <math.h>

#define EPS_LN 1e-5f

typedef __attribute__((ext_vector_type(8))) short bf16x8;
typedef __attribute__((ext_vector_type(4))) float f32x4;
typedef __attribute__((ext_vector_type(2))) unsigned short u16x2;
typedef __attribute__((ext_vector_type(4))) unsigned int u32x4;

__device__ __forceinline__ unsigned short f2bf(float f) {
    __hip_bfloat16 h = __float2bfloat16(f);
    return *reinterpret_cast<unsigned short*>(&h);
}
__device__ __forceinline__ float bf2f(unsigned short u) {
    return __uint_as_float(((unsigned)u) << 16);
}
// monotone 16-bit key of a bf16 pattern; 0 is below all real values
__device__ __forceinline__ unsigned short ok16(float f) {
    unsigned short t = f2bf(f);
    unsigned short mask = (unsigned short)(((short)t) >> 15);
    return (unsigned short)(t ^ (unsigned short)(mask | 0x8000u));
}
// decode segord entry (key16<<16; 0 == empty -> 0.0)
__device__ __forceinline__ float decseg(unsigned o) {
    if (o == 0u) return 0.f;
    unsigned k = o >> 16;
    unsigned h = (k & 0x8000u) ? (k & 0x7FFFu) : (~k & 0xFFFFu);
    return bf2f((unsigned short)h);
}

// ---------------------------------------------------------------------------
// K0: prep — pack params once per call.
// ---------------------------------------------------------------------------
__global__ __launch_bounds__(256) void prep_kernel(
    const float* __restrict__ W1, const float* __restrict__ b1,
    const float* __restrict__ g1, const float* __restrict__ be1,
    const float* __restrict__ W2,
    const float* __restrict__ W3, const float* __restrict__ W4,
    float* __restrict__ pW1e, float* __restrict__ pGB, float* __restrict__ pSG,
    unsigned short* __restrict__ pW2t,
    unsigned short* __restrict__ W3th, unsigned short* __restrict__ W3tl,
    unsigned short* __restrict__ W4th, unsigned short* __restrict__ W4tl)
{
    const int tid = threadIdx.x;
    if (tid < 64) {
        pW1e[4 * tid + 0] = W1[tid];
        pW1e[4 * tid + 1] = W1[64 + tid];
        pW1e[4 * tid + 2] = W1[128 + tid];
        pW1e[4 * tid + 3] = b1[tid];
        pGB[2 * tid + 0] = g1[tid];
        pGB[2 * tid + 1] = be1[tid];
    }
    if (tid >= 64 && tid < 78) {
        const int t = tid - 64;
        auto wcomp = [&](int k, int i) -> float {
            return (i < 3) ? W1[i * 64 + k] : b1[k];
        };
        if (t < 4) {
            float s = 0.f;
            for (int k = 0; k < 64; k++) s += wcomp(k, t);
            pSG[t] = s;
        } else {
            const int pi[10] = {0,0,0,0,1,1,1,2,2,3};
            const int pj[10] = {0,1,2,3,1,2,3,2,3,3};
            int p = t - 4;
            float s = 0.f;
            for (int k = 0; k < 64; k++) s += wcomp(k, pi[p]) * wcomp(k, pj[p]);
            pSG[4 + p] = s;
        }
    }
    for (int i = tid; i < 4096; i += 256) {
        int k = i >> 6, n = i & 63;
        pW2t[n * 72 + k] = f2bf(W2[i]);
    }
    for (int i = tid; i < 64 * 8; i += 256) {
        int n = i >> 3, k = 64 + (i & 7);
        pW2t[n * 72 + k] = 0;
    }
    for (int i = tid; i < 8192; i += 256) {
        int k = i >> 7, n = i & 127;
        float w = W3[k * 128 + n];
        unsigned short h = f2bf(w);
        W3th[n * 64 + k] = h;
        W3tl[n * 64 + k] = f2bf(w - bf2f(h));
    }
    for (int i = tid; i < 16384; i += 256) {
        int k = i >> 7, n = i & 127;
        float w = W4[k * 128 + n];
        unsigned short h = f2bf(w);
        W4th[n * 128 + k] = h;
        W4tl[n * 128 + k] = f2bf(w - bf2f(h));
    }
}

// ---------------------------------------------------------------------------
// Sort stage 1: per-block LDS hist over 2048 partitions (node>>5).
// 16384 points/block (R9: was 4096) -> nblk <= 128. Larger chunk makes s3's
// per-bin write runs 8 float4 = 128 B = one full cache line, attacking the
// scattered-write amplification R6 measured (4.2x on 16-B scatter).
// ---------------------------------------------------------------------------
__global__ __launch_bounds__(256) void s1_count(const int* __restrict__ bidx,
                                                unsigned* __restrict__ blockHist, int P) {
    __shared__ unsigned hist[2048];
    const int tid = threadIdx.x;
    for (int i = tid; i < 2048; i += 256) hist[i] = 0;
    __syncthreads();
    const int base = blockIdx.x * 16384;
#pragma unroll 4
    for (int j = 0; j < 16; j++) {
        const int p0 = base + j * 1024 + tid * 4;
        if (p0 + 3 < P) {
            int4 n4 = *(const int4*)(bidx + p0);
            atomicAdd(&hist[((unsigned)n4.x) >> 5], 1u);
            atomicAdd(&hist[((unsigned)n4.y) >> 5], 1u);
            atomicAdd(&hist[((unsigned)n4.z) >> 5], 1u);
            atomicAdd(&hist[((unsigned)n4.w) >> 5], 1u);
        } else {
            for (int p = p0; p < P && p < p0 + 4; p++)
                atomicAdd(&hist[((unsigned)bidx[p]) >> 5], 1u);
        }
    }
    __syncthreads();
    unsigned* dst = blockHist + (size_t)blockIdx.x * 2048;
    for (int i = tid; i < 2048; i += 256) dst[i] = hist[i];
}

// ---------------------------------------------------------------------------
// Sort stage 2ac (FUSED s2a+s2c): ONE column pass per bin — read the bin's
// per-block counts once, write back the per-block EXCLUSIVE scan (no
// partBase; s3 adds it at cursor-load), and emit binTotal[bin].
// ---------------------------------------------------------------------------
__global__ __launch_bounds__(256) void s2ac_scan(unsigned* __restrict__ blockHist,
                                                 unsigned* __restrict__ binTotal,
                                                 int nblk) {
    __shared__ unsigned wt0[4], wb0[4], wt1[4], wb1[4], tot0s;
    const int bin = blockIdx.x;
    const int tid = threadIdx.x;
    const int lane = tid & 63;
    const unsigned c0 = (tid < nblk) ? blockHist[(size_t)tid * 2048 + bin] : 0u;
    const unsigned c1 = (tid + 256 < nblk) ? blockHist[(size_t)(tid + 256) * 2048 + bin] : 0u;

    unsigned v0 = c0;
    for (int off = 1; off < 64; off <<= 1) {
        unsigned u = __shfl_up(v0, off);
        if (lane >= off) v0 += u;
    }
    if (lane == 63) wt0[tid >> 6] = v0;
    unsigned v1 = c1;
    for (int off = 1; off < 64; off <<= 1) {
        unsigned u = __shfl_up(v1, off);
        if (lane >= off) v1 += u;
    }
    if (lane == 63) wt1[tid >> 6] = v1;
    __syncthreads();
    if (tid == 0) {
        unsigned a = 0;
        for (int i = 0; i < 4; i++) { unsigned tmp = wt0[i]; wb0[i] = a; a += tmp; }
        tot0s = a;
        unsigned b = 0;
        for (int i = 0; i < 4; i++) { unsigned tmp = wt1[i]; wb1[i] = b; b += tmp; }
        binTotal[bin] = a + b;   // total over all blocks
    }
    __syncthreads();
    const unsigned e0 = wb0[tid >> 6] + (v0 - c0);
    const unsigned e1 = tot0s + wb1[tid >> 6] + (v1 - c1);
    if (tid < nblk) blockHist[(size_t)tid * 2048 + bin] = e0;
    if (tid + 256 < nblk) blockHist[(size_t)(tid + 256) * 2048 + bin] = e1;
}

// ---------------------------------------------------------------------------
// Sort stage 2b: exclusive scan of binTotal -> partBase[nparts+1]. 1 block.
// ---------------------------------------------------------------------------
__global__ __launch_bounds__(1024) void s2b_scan(const unsigned* __restrict__ binTotal,
                                                 unsigned* __restrict__ partBase,
                                                 int nparts, int P) {
    __shared__ unsigned wtot[16];
    const int t = threadIdx.x;
    const unsigned c0 = (2 * t < nparts) ? binTotal[2 * t] : 0u;
    const unsigned c1 = (2 * t + 1 < nparts) ? binTotal[2 * t + 1] : 0u;
    const unsigned s = c0 + c1;
    unsigned v = s;
    const int lane = t & 63;
    for (int off = 1; off < 64; off <<= 1) {
        unsigned u = __shfl_up(v, off);
        if (lane >= off) v += u;
    }
    if (lane == 63) wtot[t >> 6] = v;
    __syncthreads();
    if (t == 0) {
        unsigned a = 0;
        for (int w = 0; w < 16; w++) { unsigned tmp = wtot[w]; wtot[w] = a; a += tmp; }
    }
    __syncthreads();
    const unsigned excl = wtot[t >> 6] + (v - s);
    if (2 * t < nparts) partBase[2 * t] = excl;
    if (2 * t + 1 < nparts) partBase[2 * t + 1] = excl + c0;
    if (t == 0) partBase[nparts] = (unsigned)P;
}

// ---------------------------------------------------------------------------
// Sort stage 3: scatter (x,node) float4 into partition-grouped xb using
// deterministic cursors (LDS-local atomics only). 16384 points/block ->
// per-bin runs of ~8 float4 (128 B, one full line) instead of ~2 (32 B).
// ---------------------------------------------------------------------------
__global__ __launch_bounds__(256) void s3_scatter(const int* __restrict__ bidx,
                                                  const float* __restrict__ x,
                                                  const unsigned* __restrict__ blockCursor,
                                                  const unsigned* __restrict__ partBase,
                                                  float4* __restrict__ xb, int P) {
    __shared__ unsigned cur[2048];
    const int tid = threadIdx.x;
    const unsigned* src = blockCursor + (size_t)blockIdx.x * 2048;
    for (int i = tid; i < 2048; i += 256) cur[i] = src[i] + partBase[i];
    __syncthreads();
    const int base = blockIdx.x * 16384;
#pragma unroll 4
    for (int j = 0; j < 16; j++) {
        const int p0 = base + j * 1024 + tid * 4;
        if (p0 + 3 < P) {
            int4 n4 = *(const int4*)(bidx + p0);
            const float4* xv = (const float4*)(x + 3 * (size_t)p0);
            float4 a = xv[0], b = xv[1], c = xv[2];
            const float xs[12] = {a.x, a.y, a.z, a.w, b.x, b.y, b.z, b.w,
                                  c.x, c.y, c.z, c.w};
            const unsigned nn[4] = {(unsigned)n4.x, (unsigned)n4.y,
                                    (unsigned)n4.z, (unsigned)n4.w};
#pragma unroll
            for (int u = 0; u < 4; u++) {
                const unsigned dst = atomicAdd(&cur[nn[u] >> 5], 1u);
                xb[dst] = make_float4(xs[3 * u], xs[3 * u + 1], xs[3 * u + 2],
                                      __uint_as_float(nn[u]));
            }
        } else {
            for (int u = 0; u < 4; u++) {
                const int p = p0 + u;
                if (p < P) {
                    const unsigned n = (unsigned)bidx[p];
                    const unsigned dst = atomicAdd(&cur[n >> 5], 1u);
                    xb[dst] = make_float4(x[3 * p], x[3 * p + 1], x[3 * p + 2],
                                          __uint_as_float(n));
                }
            }
        }
    }
}

// ---------------------------------------------------------------------------
// Sort stage 4: per-partition CSR + node-sort. One block per partition.
// ---------------------------------------------------------------------------
__global__ __launch_bounds__(256) void s4_csr(const unsigned* __restrict__ partBase,
                                              unsigned* __restrict__ offsets,
                                              float4* __restrict__ xb, int N) {
    __shared__ float4 stage[1600];
    __shared__ unsigned hist[32], cur[32];
    const int tid = threadIdx.x;
    const int p = blockIdx.x;
    const unsigned start = partBase[p], end = partBase[p + 1];
    unsigned cnt = end - start;
    if (cnt > 1600u) cnt = 1600u;
    if (tid < 32) hist[tid] = 0;
    __syncthreads();
    for (unsigned k = tid; k < cnt; k += 256) {
        float4 r = xb[start + k];
        stage[k] = r;
        atomicAdd(&hist[__float_as_uint(r.w) & 31u], 1u);
    }
    __syncthreads();
    if (tid < 64) {
        const unsigned c = (tid < 32) ? hist[tid] : 0u;
        unsigned v = c;
        for (int off = 1; off < 32; off <<= 1) {
            unsigned u = __shfl_up(v, off);
            if (tid >= off) v += u;
        }
        if (tid < 32) {
            const unsigned excl = v - c;
            const int node = p * 32 + tid;
            if (node < N) offsets[node] = start + excl;
            cur[tid] = start + excl;
            if (node == N - 1) offsets[N] = start + excl + c;
        }
    }
    __syncthreads();
    for (unsigned k = tid; k < cnt; k += 256) {
        float4 r = stage[k];
        const unsigned dst = atomicAdd(&cur[__float_as_uint(r.w) & 31u], 1u);
        xb[dst] = r;
    }
}

// ---------------------------------------------------------------------------
// K4: fused MLP1 + chunk-segmented max pool — EXACT measured-good version
// (92.6 µs, FETCH 17 MB / WRITE 18 MB, VALUBusy 58%). FROZEN.
// ---------------------------------------------------------------------------
__global__ __launch_bounds__(256, 3) void fused_mlp1_pool_kernel(
    const float4* __restrict__ xb, const unsigned* __restrict__ offsets,
    const float* __restrict__ pW1e, const float* __restrict__ pGB,
    const float* __restrict__ pSG, const unsigned short* __restrict__ pW2t,
    const float* __restrict__ b2,
    unsigned* __restrict__ segord, int P)
{
    __shared__ __align__(16) unsigned short shbt[64 * 260];  // 33.3 KB, [ch][row]
    __shared__ unsigned sn01[2];

    const int tid  = threadIdx.x;
    const int wv   = tid >> 6;
    const int lane = tid & 63;
    const int m    = lane & 15;
    const int quad = lane >> 4;
    const int base = blockIdx.x * 256;
    const int pos  = base + tid;
    const bool valid = (pos < P);

    // ---- W2 B-fragments + bias: straight from global into registers
    bf16x8 bfrag[4][2];
    float bc[4];
#pragma unroll
    for (int nt = 0; nt < 4; nt++) {
        bc[nt] = b2[nt * 16 + m];
#pragma unroll
        for (int s = 0; s < 2; s++)
            bfrag[nt][s] = *reinterpret_cast<const bf16x8*>(
                &pW2t[(nt * 16 + m) * 72 + s * 32 + quad * 8]);
    }

    // ---- own row load + LN stats via Gram trick
    float x0 = 0.f, x1 = 0.f, x2 = 0.f;
    if (valid) {
        float4 v = xb[pos];
        x0 = v.x; x1 = v.y; x2 = v.z;
        unsigned node = __float_as_uint(v.w);
        if (tid == 0) sn01[0] = node;
        if (tid == 255 || pos == P - 1) sn01[1] = node;
    }

    float rs, r2;
    {
        const float S0 = pSG[0], S1 = pSG[1], S2 = pSG[2], S3 = pSG[3];
        const float g00 = pSG[4], g01 = pSG[5], g02 = pSG[6], g03 = pSG[7];
        const float g11 = pSG[8], g12 = pSG[9], g13 = pSG[10];
        const float g22 = pSG[11], g23 = pSG[12], g33 = pSG[13];

        const float mu = fmaf(S0, x0, fmaf(S1, x1, fmaf(S2, x2, S3))) * (1.f / 64.f);
        float q = g33;
        q = fmaf(g00, x0 * x0, q);
        q = fmaf(g11, x1 * x1, q);
        q = fmaf(g22, x2 * x2, q);
        float c = fmaf(g01, x1, fmaf(g02, x2, g03));
        q = fmaf(2.f * x0, c, q);
        q = fmaf(2.f * x1, fmaf(g12, x2, g13), q);
        q = fmaf(2.f * x2, g23, q);
        float var = q * (1.f / 64.f) - mu * mu;
        var = var > 0.f ? var : 0.f;
        rs = rsqrtf(var + EPS_LN);
        r2 = -mu * rs;
    }

    // ---- deliver x/stats of the 4 rows this lane serves (wave-local rows)
    float xr0[4], xr1[4], xr2[4], rsr[4], r2r[4];
#pragma unroll
    for (int rt = 0; rt < 4; rt++) {
        const int src = rt * 16 + m;
        xr0[rt] = __shfl(x0, src);
        xr1[rt] = __shfl(x1, src);
        xr2[rt] = __shfl(x2, src);
        rsr[rt] = __shfl(rs, src);
        r2r[rt] = __shfl(r2, src);
    }

    // ---- Phase 1: layer-1 + LN + ReLU, computed directly in A-frag layout.
    u32x4 afr[4][2];
    {
        const float4* pw = (const float4*)pW1e;
        const float2* pg = (const float2*)pGB;
#pragma unroll
        for (int s = 0; s < 2; s++) {
#pragma unroll
            for (int up = 0; up < 4; up++) {
                const int ch = s * 32 + quad * 8 + up * 2;
                const float4 wA = pw[ch], wB = pw[ch + 1];
                const float2 gA = pg[ch], gB = pg[ch + 1];
#pragma unroll
                for (int rt = 0; rt < 4; rt++) {
                    float y0 = fmaf(xr0[rt], wA.x, fmaf(xr1[rt], wA.y,
                               fmaf(xr2[rt], wA.z, wA.w)));
                    float y1 = fmaf(xr0[rt], wB.x, fmaf(xr1[rt], wB.y,
                               fmaf(xr2[rt], wB.z, wB.w)));
                    float a0 = fmaf(fmaf(y0, rsr[rt], r2r[rt]), gA.x, gA.y);
                    float a1 = fmaf(fmaf(y1, rsr[rt], r2r[rt]), gB.x, gB.y);
                    a0 = a0 > 0.f ? a0 : 0.f;
                    a1 = a1 > 0.f ? a1 : 0.f;
                    afr[rt][s][up] = (unsigned)f2bf(a0) | ((unsigned)f2bf(a1) << 16);
                }
            }
        }
    }

    // ---- Phase 2: h = a @ W2 + b2 via MFMA; transposed ordkey16 store
#pragma unroll
    for (int rt = 0; rt < 4; rt++) {
        const int orow = wv * 64 + rt * 16 + quad * 4;   // C rows this lane owns
        const bf16x8 af0 = __builtin_bit_cast(bf16x8, afr[rt][0]);
        const bf16x8 af1 = __builtin_bit_cast(bf16x8, afr[rt][1]);
#pragma unroll
        for (int nt = 0; nt < 4; nt++) {
            f32x4 acc = {bc[nt], bc[nt], bc[nt], bc[nt]};
            acc = __builtin_amdgcn_mfma_f32_16x16x32_bf16(af0, bfrag[nt][0], acc, 0, 0, 0);
            acc = __builtin_amdgcn_mfma_f32_16x16x32_bf16(af1, bfrag[nt][1], acc, 0, 0, 0);
            const int col = nt * 16 + m;
            uint2 pk;
            pk.x = (unsigned)ok16(acc[0]) | ((unsigned)ok16(acc[1]) << 16);
            pk.y = (unsigned)ok16(acc[2]) | ((unsigned)ok16(acc[3]) << 16);
            *reinterpret_cast<uint2*>(&shbt[col * 260 + orow]) = pk;
        }
    }
    __syncthreads();

    // ---- Phase 3: segmented max, contiguous b64 reads + packed u16 max
    const int nValid = (P - base < 256) ? (P - base) : 256;
    if (nValid <= 0) return;
    const unsigned n0 = sn01[0];
    const unsigned n1 = sn01[1];
    const unsigned bEnd = (unsigned)(base + nValid);
    const int wave = tid >> 6;
    const int ch   = tid & 63;
    const unsigned short* rowp = &shbt[ch * 260];

    for (unsigned n = n0 + (unsigned)wave; n <= n1; n += 4) {
        const unsigned s = offsets[n];
        const unsigned e = offsets[n + 1];
        int lo = (int)(s > (unsigned)base ? s : (unsigned)base) - base;
        int hi = (int)(e < bEnd ? e : bEnd) - base;
        if (hi <= lo) continue;   // empty node inside range: leave 0
        u16x2 accv = {0, 0};
        unsigned short accs = 0;
        for (int r = lo & ~3; r < hi; r += 4) {
            uint2 d = *reinterpret_cast<const uint2*>(rowp + r);
            if (r >= lo && r + 4 <= hi) {
                u16x2 a = __builtin_bit_cast(u16x2, d.x);
                u16x2 b = __builtin_bit_cast(u16x2, d.y);
                accv = __builtin_elementwise_max(accv, __builtin_elementwise_max(a, b));
            } else {
                unsigned short v0 = (unsigned short)(d.x & 0xFFFFu);
                unsigned short v1 = (unsigned short)(d.x >> 16);
                unsigned short v2 = (unsigned short)(d.y & 0xFFFFu);
                unsigned short v3 = (unsigned short)(d.y >> 16);
                if (r     >= lo && r     < hi && v0 > accs) accs = v0;
                if (r + 1 >= lo && r + 1 < hi && v1 > accs) accs = v1;
                if (r + 2 >= lo && r + 2 < hi && v2 > accs) accs = v2;
                if (r + 3 >= lo && r + 3 < hi && v3 > accs) accs = v3;
            }
        }
        unsigned short k = accv.x > accv.y ? accv.x : accv.y;
        if (accs > k) k = accs;
        const unsigned key = ((unsigned)k) << 16;
        unsigned* dst = &segord[(size_t)n * 64 + ch];
        if (s >= (unsigned)base && e <= bEnd) *dst = key;   // sole writer
        else atomicMax(dst, key);                            // boundary node
    }
}

// ---------------------------------------------------------------------------
// K5: MLP2 fully in MFMA with split-bf16. Grid 512 (measured better than
// 2048 in R5 A/B: +13 µs at 2048).
// ---------------------------------------------------------------------------
__global__ __launch_bounds__(256) void mlp2_mfma_kernel(
    const unsigned* __restrict__ segord,
    const unsigned short* __restrict__ W3th, const unsigned short* __restrict__ W3tl,
    const unsigned short* __restrict__ W4th, const unsigned short* __restrict__ W4tl,
    const float* __restrict__ b3, const float* __restrict__ g2,
    const float* __restrict__ be2, const float* __restrict__ b4,
    float* __restrict__ out, int N)
{
    __shared__ __align__(16) unsigned short sa2[32 * 72];
    __shared__ __align__(16) float st[32 * 132];
    __shared__ __align__(16) unsigned short suh[32 * 136];
    __shared__ __align__(16) unsigned short sul[32 * 136];
    __shared__ float2 sred[32][8];
    __shared__ float sg2[128], sbe2[128];

    const int tid  = threadIdx.x;
    const int wv   = tid >> 6;
    const int lane = tid & 63;
    const int m    = lane & 15;
    const int quad = lane >> 4;

    if (tid < 128) { sg2[tid] = g2[tid]; sbe2[tid] = be2[tid]; }

    bf16x8 fw3h[2][2], fw3l[2][2];
    bf16x8 fw4h[2][4], fw4l[2][4];
    float bias3[2], bias4[2];
#pragma unroll
    for (int nti = 0; nti < 2; nti++) {
        const int nrow = (wv * 2 + nti) * 16 + m;
        bias3[nti] = b3[nrow];
        bias4[nti] = b4[nrow];
#pragma unroll
        for (int ks = 0; ks < 2; ks++) {
            fw3h[nti][ks] = *reinterpret_cast<const bf16x8*>(&W3th[nrow * 64 + ks * 32 + quad * 8]);
            fw3l[nti][ks] = *reinterpret_cast<const bf16x8*>(&W3tl[nrow * 64 + ks * 32 + quad * 8]);
        }
#pragma unroll
        for (int ks = 0; ks < 4; ks++) {
            fw4h[nti][ks] = *reinterpret_cast<const bf16x8*>(&W4th[nrow * 128 + ks * 32 + quad * 8]);
            fw4l[nti][ks] = *reinterpret_cast<const bf16x8*>(&W4tl[nrow * 128 + ks * 32 + quad * 8]);
        }
    }
    __syncthreads();

    for (int nb = blockIdx.x * 32; nb < N; nb += gridDim.x * 32) {
        {
            const int node = tid >> 3;
            const int k8   = (tid & 7) * 8;
            const uint4* sp = (const uint4*)&segord[(size_t)(nb + node) * 64 + k8];
            uint4 q0 = sp[0], q1 = sp[1];
            bf16x8 v;
            v[0] = (short)f2bf(decseg(q0.x));
            v[1] = (short)f2bf(decseg(q0.y));
            v[2] = (short)f2bf(decseg(q0.z));
            v[3] = (short)f2bf(decseg(q0.w));
            v[4] = (short)f2bf(decseg(q1.x));
            v[5] = (short)f2bf(decseg(q1.y));
            v[6] = (short)f2bf(decseg(q1.z));
            v[7] = (short)f2bf(decseg(q1.w));
            *reinterpret_cast<bf16x8*>(&sa2[node * 72 + k8]) = v;
        }
        __syncthreads();

#pragma unroll
        for (int mt = 0; mt < 2; mt++) {
            bf16x8 a0 = *reinterpret_cast<const bf16x8*>(&sa2[(mt * 16 + m) * 72 + quad * 8]);
            bf16x8 a1 = *reinterpret_cast<const bf16x8*>(&sa2[(mt * 16 + m) * 72 + 32 + quad * 8]);
#pragma unroll
            for (int nti = 0; nti < 2; nti++) {
                f32x4 acc = {bias3[nti], bias3[nti], bias3[nti], bias3[nti]};
                acc = __builtin_amdgcn_mfma_f32_16x16x32_bf16(a0, fw3h[nti][0], acc, 0, 0, 0);
                acc = __builtin_amdgcn_mfma_f32_16x16x32_bf16(a1, fw3h[nti][1], acc, 0, 0, 0);
                acc = __builtin_amdgcn_mfma_f32_16x16x32_bf16(a0, fw3l[nti][0], acc, 0, 0, 0);
                acc = __builtin_amdgcn_mfma_f32_16x16x32_bf16(a1, fw3l[nti][1], acc, 0, 0, 0);
#pragma unroll
                for (int r = 0; r < 4; r++)
                    st[(mt * 16 + quad * 4 + r) * 132 + (wv * 2 + nti) * 16 + m] = acc[r];
            }
        }
        __syncthreads();

        {
            const int node = tid >> 3;
            const int seg  = tid & 7;
            const float4* rp = (const float4*)&st[node * 132 + seg * 16];
            float4 v0 = rp[0], v1 = rp[1], v2 = rp[2], v3 = rp[3];
            float s1 = v0.x + v0.y + v0.z + v0.w + v1.x + v1.y + v1.z + v1.w
                     + v2.x + v2.y + v2.z + v2.w + v3.x + v3.y + v3.z + v3.w;
            float s2 = 0.f;
            s2 = fmaf(v0.x, v0.x, s2); s2 = fmaf(v0.y, v0.y, s2); s2 = fmaf(v0.z, v0.z, s2); s2 = fmaf(v0.w, v0.w, s2);
            s2 = fmaf(v1.x, v1.x, s2); s2 = fmaf(v1.y, v1.y, s2); s2 = fmaf(v1.z, v1.z, s2); s2 = fmaf(v1.w, v1.w, s2);
            s2 = fmaf(v2.x, v2.x, s2); s2 = fmaf(v2.y, v2.y, s2); s2 = fmaf(v2.z, v2.z, s2); s2 = fmaf(v2.w, v2.w, s2);
            s2 = fmaf(v3.x, v3.x, s2); s2 = fmaf(v3.y, v3.y, s2); s2 = fmaf(v3.z, v3.z, s2); s2 = fmaf(v3.w, v3.w, s2);
            sred[node][seg] = make_float2(s1, s2);
            __syncthreads();

            float t1 = 0.f, t2 = 0.f;
#pragma unroll
            for (int i = 0; i < 8; i++) { float2 r = sred[node][i]; t1 += r.x; t2 += r.y; }
            const float mu  = t1 * (1.f / 128.f);
            float var = t2 * (1.f / 128.f) - mu * mu;
            var = var > 0.f ? var : 0.f;
            const float rsd = rsqrtf(var + EPS_LN);

            float tv[16] = {v0.x, v0.y, v0.z, v0.w, v1.x, v1.y, v1.z, v1.w,
                            v2.x, v2.y, v2.z, v2.w, v3.x, v3.y, v3.z, v3.w};
            bf16x8 vh[2], vl[2];
#pragma unroll
            for (int i = 0; i < 16; i++) {
                const int j = seg * 16 + i;
                float u = fmaf((tv[i] - mu) * rsd, sg2[j], sbe2[j]);
                u = u > 0.f ? u : 0.f;
                unsigned short uh = f2bf(u);
                unsigned short ul = f2bf(u - bf2f(uh));
                vh[i >> 3][i & 7] = (short)uh;
                vl[i >> 3][i & 7] = (short)ul;
            }
            *reinterpret_cast<bf16x8*>(&suh[node * 136 + seg * 16])     = vh[0];
            *reinterpret_cast<bf16x8*>(&suh[node * 136 + seg * 16 + 8]) = vh[1];
            *reinterpret_cast<bf16x8*>(&sul[node * 136 + seg * 16])     = vl[0];
            *reinterpret_cast<bf16x8*>(&sul[node * 136 + seg * 16 + 8]) = vl[1];
        }
        __syncthreads();

#pragma unroll
        for (int mt = 0; mt < 2; mt++) {
            bf16x8 ah[4], al[4];
#pragma unroll
            for (int ks = 0; ks < 4; ks++) {
                ah[ks] = *reinterpret_cast<const bf16x8*>(&suh[(mt * 16 + m) * 136 + ks * 32 + quad * 8]);
                al[ks] = *reinterpret_cast<const bf16x8*>(&sul[(mt * 16 + m) * 136 + ks * 32 + quad * 8]);
            }
#pragma unroll
            for (int nti = 0; nti < 2; nti++) {
                f32x4 acc = {bias4[nti], bias4[nti], bias4[nti], bias4[nti]};
#pragma unroll
                for (int ks = 0; ks < 4; ks++) {
                    acc = __builtin_amdgcn_mfma_f32_16x16x32_bf16(ah[ks], fw4h[nti][ks], acc, 0, 0, 0);
                    acc = __builtin_amdgcn_mfma_f32_16x16x32_bf16(al[ks], fw4h[nti][ks], acc, 0, 0, 0);
                    acc = __builtin_amdgcn_mfma_f32_16x16x32_bf16(ah[ks], fw4l[nti][ks], acc, 0, 0, 0);
                }
#pragma unroll
                for (int r = 0; r < 4; r++) {
                    const int node = nb + mt * 16 + quad * 4 + r;
                    if (node < N)
                        out[(size_t)node * 128 + (wv * 2 + nti) * 16 + m] = acc[r];
                }
            }
        }
        __syncthreads();
    }
}

extern "C" void kernel_launch(void* const* d_in, const int* in_sizes, int n_in,
                              void* d_out, int out_size, void* d_ws, size_t ws_size,
                              hipStream_t stream) {
    const float* x    = (const float*)d_in[0];
    const int*   bidx = (const int*)d_in[1];
    const float* W1  = (const float*)d_in[3];
    const float* b1  = (const float*)d_in[4];
    const float* g1  = (const float*)d_in[5];
    const float* be1 = (const float*)d_in[6];
    const float* W2  = (const float*)d_in[7];
    const float* b2  = (const float*)d_in[8];
    const float* W3  = (const float*)d_in[9];
    const float* b3  = (const float*)d_in[10];
    const float* g2  = (const float*)d_in[11];
    const float* be2 = (const float*)d_in[12];
    const float* W4  = (const float*)d_in[13];
    const float* b4  = (const float*)d_in[14];

    const int P = in_sizes[0] / 3;
    const int N = out_size / 128;
    const int nparts = (N + 31) >> 5;            // <= 2048
    const int nblk   = (P + 16383) / 16384;      // <= 128 (16384 pts/block)

    uintptr_t w = (uintptr_t)d_ws;
    auto align = [](uintptr_t v) { return (v + 255) & ~(uintptr_t)255; };
    unsigned* blockHist = (unsigned*)align(w);     w = (uintptr_t)(blockHist + (size_t)nblk * 2048);
    unsigned* binTotal  = (unsigned*)align(w);     w = (uintptr_t)(binTotal  + 2048);
    unsigned* partBase  = (unsigned*)align(w);     w = (uintptr_t)(partBase  + 2049);
    unsigned* offsets   = (unsigned*)align(w);     w = (uintptr_t)(offsets   + N + 1);
    float4*   xb        = (float4*)align(w);       w = (uintptr_t)(xb        + P);
    unsigned* segord    = (unsigned*)align(w);     w = (uintptr_t)(segord    + (size_t)N * 64);
    float*    pW1e      = (float*)align(w);        w = (uintptr_t)(pW1e      + 256);
    float*    pGB       = (float*)align(w);        w = (uintptr_t)(pGB       + 128);
    float*    pSG       = (float*)align(w);        w = (uintptr_t)(pSG       + 16);
    unsigned short* pW2t = (unsigned short*)align(w); w = (uintptr_t)(pW2t + 64 * 72);
    unsigned short* W3th = (unsigned short*)align(w); w = (uintptr_t)(W3th + 128 * 64);
    unsigned short* W3tl = (unsigned short*)align(w); w = (uintptr_t)(W3tl + 128 * 64);
    unsigned short* W4th = (unsigned short*)align(w); w = (uintptr_t)(W4th + 128 * 128);
    unsigned short* W4tl = (unsigned short*)align(w); w = (uintptr_t)(W4tl + 128 * 128);

    hipMemsetAsync(segord, 0, (size_t)N * 64 * sizeof(unsigned), stream);

    prep_kernel<<<1, 256, 0, stream>>>(W1, b1, g1, be1, W2, W3, W4,
                                       pW1e, pGB, pSG, pW2t, W3th, W3tl, W4th, W4tl);

    s1_count<<<nblk, 256, 0, stream>>>(bidx, blockHist, P);
    s2ac_scan<<<nparts, 256, 0, stream>>>(blockHist, binTotal, nblk);
    s2b_scan<<<1, 1024, 0, stream>>>(binTotal, partBase, nparts, P);
    s3_scatter<<<nblk, 256, 0, stream>>>(bidx, x, blockHist, partBase, xb, P);
    s4_csr<<<nparts, 256, 0, stream>>>(partBase, offsets, xb, N);

    fused_mlp1_pool_kernel<<<(P + 255) / 256, 256, 0, stream>>>(
        xb, offsets, pW1e, pGB, pSG, pW2t, b2, segord, P);

    mlp2_mfma_kernel<<<512, 256, 0, stream>>>(
        segord, W3th, W3tl, W4th, W4tl, b3, g2, be2, b4, (float*)d_out, N);
}

// Round 10
// 310.314 us; speedup vs baseline: 2.0302x; 1.0581x over previous
//
#include <hip/hip_runtime.h>
#include <hip/hip_bf16.h>
#include <math.h>

#define EPS_LN 1e-5f

typedef __attribute__((ext_vector_type(8))) short bf16x8;
typedef __attribute__((ext_vector_type(4))) float f32x4;
typedef __attribute__((ext_vector_type(2))) unsigned short u16x2;
typedef __attribute__((ext_vector_type(4))) unsigned int u32x4;

__device__ __forceinline__ unsigned short f2bf(float f) {
    __hip_bfloat16 h = __float2bfloat16(f);
    return *reinterpret_cast<unsigned short*>(&h);
}
__device__ __forceinline__ float bf2f(unsigned short u) {
    return __uint_as_float(((unsigned)u) << 16);
}
// monotone 16-bit key of a bf16 pattern; 0 is below all real values
__device__ __forceinline__ unsigned short ok16(float f) {
    unsigned short t = f2bf(f);
    unsigned short mask = (unsigned short)(((short)t) >> 15);
    return (unsigned short)(t ^ (unsigned short)(mask | 0x8000u));
}
// decode segord entry (key16<<16; 0 == empty -> 0.0)
__device__ __forceinline__ float decseg(unsigned o) {
    if (o == 0u) return 0.f;
    unsigned k = o >> 16;
    unsigned h = (k & 0x8000u) ? (k & 0x7FFFu) : (~k & 0xFFFFu);
    return bf2f((unsigned short)h);
}

// ---------------------------------------------------------------------------
// s1_fused: per-block LDS hist over 2048 partitions (16384 pts/block,
// nblk <= 128) + grid-strided segord zeroing (replaces hipMemsetAsync)
// + prep packing in the extra block (blockIdx == nblk). Launch count 9 -> 7;
// tests the per-launch-gap hypothesis for the unexplained residual.
// ---------------------------------------------------------------------------
__global__ __launch_bounds__(256) void s1_fused(
    const int* __restrict__ bidx, unsigned* __restrict__ blockHist, int P, int nblk,
    unsigned* __restrict__ segord, int segWords,
    const float* __restrict__ W1, const float* __restrict__ b1,
    const float* __restrict__ g1, const float* __restrict__ be1,
    const float* __restrict__ W2,
    const float* __restrict__ W3, const float* __restrict__ W4,
    float* __restrict__ pW1e, float* __restrict__ pGB, float* __restrict__ pSG,
    unsigned short* __restrict__ pW2t,
    unsigned short* __restrict__ W3th, unsigned short* __restrict__ W3tl,
    unsigned short* __restrict__ W4th, unsigned short* __restrict__ W4tl)
{
    const int tid = threadIdx.x;

    if ((int)blockIdx.x == nblk) {
        // ---- prep body (was prep_kernel), one block
        if (tid < 64) {
            pW1e[4 * tid + 0] = W1[tid];
            pW1e[4 * tid + 1] = W1[64 + tid];
            pW1e[4 * tid + 2] = W1[128 + tid];
            pW1e[4 * tid + 3] = b1[tid];
            pGB[2 * tid + 0] = g1[tid];
            pGB[2 * tid + 1] = be1[tid];
        }
        if (tid >= 64 && tid < 78) {
            const int t = tid - 64;
            auto wcomp = [&](int k, int i) -> float {
                return (i < 3) ? W1[i * 64 + k] : b1[k];
            };
            if (t < 4) {
                float s = 0.f;
                for (int k = 0; k < 64; k++) s += wcomp(k, t);
                pSG[t] = s;
            } else {
                const int pi[10] = {0,0,0,0,1,1,1,2,2,3};
                const int pj[10] = {0,1,2,3,1,2,3,2,3,3};
                int p = t - 4;
                float s = 0.f;
                for (int k = 0; k < 64; k++) s += wcomp(k, pi[p]) * wcomp(k, pj[p]);
                pSG[4 + p] = s;
            }
        }
        for (int i = tid; i < 4096; i += 256) {
            int k = i >> 6, n = i & 63;
            pW2t[n * 72 + k] = f2bf(W2[i]);
        }
        for (int i = tid; i < 64 * 8; i += 256) {
            int n = i >> 3, k = 64 + (i & 7);
            pW2t[n * 72 + k] = 0;
        }
        for (int i = tid; i < 8192; i += 256) {
            int k = i >> 7, n = i & 127;
            float w = W3[k * 128 + n];
            unsigned short h = f2bf(w);
            W3th[n * 64 + k] = h;
            W3tl[n * 64 + k] = f2bf(w - bf2f(h));
        }
        for (int i = tid; i < 16384; i += 256) {
            int k = i >> 7, n = i & 127;
            float w = W4[k * 128 + n];
            unsigned short h = f2bf(w);
            W4th[n * 128 + k] = h;
            W4tl[n * 128 + k] = f2bf(w - bf2f(h));
        }
        return;
    }

    // ---- segord zeroing, grid-strided uint4 over the s1 blocks
    {
        uint4* sz = (uint4*)segord;
        const int nq = segWords >> 2;                 // uint4 count
        const int stride = nblk * 256;
        const uint4 z = make_uint4(0u, 0u, 0u, 0u);
        for (int i = blockIdx.x * 256 + tid; i < nq; i += stride) sz[i] = z;
    }

    // ---- s1 histogram body
    __shared__ unsigned hist[2048];
    for (int i = tid; i < 2048; i += 256) hist[i] = 0;
    __syncthreads();
    const int base = blockIdx.x * 16384;
#pragma unroll 4
    for (int j = 0; j < 16; j++) {
        const int p0 = base + j * 1024 + tid * 4;
        if (p0 + 3 < P) {
            int4 n4 = *(const int4*)(bidx + p0);
            atomicAdd(&hist[((unsigned)n4.x) >> 5], 1u);
            atomicAdd(&hist[((unsigned)n4.y) >> 5], 1u);
            atomicAdd(&hist[((unsigned)n4.z) >> 5], 1u);
            atomicAdd(&hist[((unsigned)n4.w) >> 5], 1u);
        } else {
            for (int p = p0; p < P && p < p0 + 4; p++)
                atomicAdd(&hist[((unsigned)bidx[p]) >> 5], 1u);
        }
    }
    __syncthreads();
    unsigned* dst = blockHist + (size_t)blockIdx.x * 2048;
    for (int i = tid; i < 2048; i += 256) dst[i] = hist[i];
}

// ---------------------------------------------------------------------------
// Sort stage 2ac (FUSED s2a+s2c): ONE column pass per bin — read the bin's
// per-block counts once, write back the per-block EXCLUSIVE scan (no
// partBase; s3 adds it at cursor-load), and emit binTotal[bin].
// ---------------------------------------------------------------------------
__global__ __launch_bounds__(256) void s2ac_scan(unsigned* __restrict__ blockHist,
                                                 unsigned* __restrict__ binTotal,
                                                 int nblk) {
    __shared__ unsigned wt0[4], wb0[4], wt1[4], wb1[4], tot0s;
    const int bin = blockIdx.x;
    const int tid = threadIdx.x;
    const int lane = tid & 63;
    const unsigned c0 = (tid < nblk) ? blockHist[(size_t)tid * 2048 + bin] : 0u;
    const unsigned c1 = (tid + 256 < nblk) ? blockHist[(size_t)(tid + 256) * 2048 + bin] : 0u;

    unsigned v0 = c0;
    for (int off = 1; off < 64; off <<= 1) {
        unsigned u = __shfl_up(v0, off);
        if (lane >= off) v0 += u;
    }
    if (lane == 63) wt0[tid >> 6] = v0;
    unsigned v1 = c1;
    for (int off = 1; off < 64; off <<= 1) {
        unsigned u = __shfl_up(v1, off);
        if (lane >= off) v1 += u;
    }
    if (lane == 63) wt1[tid >> 6] = v1;
    __syncthreads();
    if (tid == 0) {
        unsigned a = 0;
        for (int i = 0; i < 4; i++) { unsigned tmp = wt0[i]; wb0[i] = a; a += tmp; }
        tot0s = a;
        unsigned b = 0;
        for (int i = 0; i < 4; i++) { unsigned tmp = wt1[i]; wb1[i] = b; b += tmp; }
        binTotal[bin] = a + b;   // total over all blocks
    }
    __syncthreads();
    const unsigned e0 = wb0[tid >> 6] + (v0 - c0);
    const unsigned e1 = tot0s + wb1[tid >> 6] + (v1 - c1);
    if (tid < nblk) blockHist[(size_t)tid * 2048 + bin] = e0;
    if (tid + 256 < nblk) blockHist[(size_t)(tid + 256) * 2048 + bin] = e1;
}

// ---------------------------------------------------------------------------
// Sort stage 2b: exclusive scan of binTotal -> partBase[nparts+1]. 1 block.
// ---------------------------------------------------------------------------
__global__ __launch_bounds__(1024) void s2b_scan(const unsigned* __restrict__ binTotal,
                                                 unsigned* __restrict__ partBase,
                                                 int nparts, int P) {
    __shared__ unsigned wtot[16];
    const int t = threadIdx.x;
    const unsigned c0 = (2 * t < nparts) ? binTotal[2 * t] : 0u;
    const unsigned c1 = (2 * t + 1 < nparts) ? binTotal[2 * t + 1] : 0u;
    const unsigned s = c0 + c1;
    unsigned v = s;
    const int lane = t & 63;
    for (int off = 1; off < 64; off <<= 1) {
        unsigned u = __shfl_up(v, off);
        if (lane >= off) v += u;
    }
    if (lane == 63) wtot[t >> 6] = v;
    __syncthreads();
    if (t == 0) {
        unsigned a = 0;
        for (int w = 0; w < 16; w++) { unsigned tmp = wtot[w]; wtot[w] = a; a += tmp; }
    }
    __syncthreads();
    const unsigned excl = wtot[t >> 6] + (v - s);
    if (2 * t < nparts) partBase[2 * t] = excl;
    if (2 * t + 1 < nparts) partBase[2 * t + 1] = excl + c0;
    if (t == 0) partBase[nparts] = (unsigned)P;
}

// ---------------------------------------------------------------------------
// Sort stage 3: scatter (x,node) float4 into partition-grouped xb using
// deterministic cursors (LDS-local atomics only). 16384 points/block ->
// per-bin runs of ~8 float4 (128 B, one full line).
// ---------------------------------------------------------------------------
__global__ __launch_bounds__(256) void s3_scatter(const int* __restrict__ bidx,
                                                  const float* __restrict__ x,
                                                  const unsigned* __restrict__ blockCursor,
                                                  const unsigned* __restrict__ partBase,
                                                  float4* __restrict__ xb, int P) {
    __shared__ unsigned cur[2048];
    const int tid = threadIdx.x;
    const unsigned* src = blockCursor + (size_t)blockIdx.x * 2048;
    for (int i = tid; i < 2048; i += 256) cur[i] = src[i] + partBase[i];
    __syncthreads();
    const int base = blockIdx.x * 16384;
#pragma unroll 4
    for (int j = 0; j < 16; j++) {
        const int p0 = base + j * 1024 + tid * 4;
        if (p0 + 3 < P) {
            int4 n4 = *(const int4*)(bidx + p0);
            const float4* xv = (const float4*)(x + 3 * (size_t)p0);
            float4 a = xv[0], b = xv[1], c = xv[2];
            const float xs[12] = {a.x, a.y, a.z, a.w, b.x, b.y, b.z, b.w,
                                  c.x, c.y, c.z, c.w};
            const unsigned nn[4] = {(unsigned)n4.x, (unsigned)n4.y,
                                    (unsigned)n4.z, (unsigned)n4.w};
#pragma unroll
            for (int u = 0; u < 4; u++) {
                const unsigned dst = atomicAdd(&cur[nn[u] >> 5], 1u);
                xb[dst] = make_float4(xs[3 * u], xs[3 * u + 1], xs[3 * u + 2],
                                      __uint_as_float(nn[u]));
            }
        } else {
            for (int u = 0; u < 4; u++) {
                const int p = p0 + u;
                if (p < P) {
                    const unsigned n = (unsigned)bidx[p];
                    const unsigned dst = atomicAdd(&cur[n >> 5], 1u);
                    xb[dst] = make_float4(x[3 * p], x[3 * p + 1], x[3 * p + 2],
                                          __uint_as_float(n));
                }
            }
        }
    }
}

// ---------------------------------------------------------------------------
// Sort stage 4: per-partition CSR + node-sort. One block per partition.
// ---------------------------------------------------------------------------
__global__ __launch_bounds__(256) void s4_csr(const unsigned* __restrict__ partBase,
                                              unsigned* __restrict__ offsets,
                                              float4* __restrict__ xb, int N) {
    __shared__ float4 stage[1600];
    __shared__ unsigned hist[32], cur[32];
    const int tid = threadIdx.x;
    const int p = blockIdx.x;
    const unsigned start = partBase[p], end = partBase[p + 1];
    unsigned cnt = end - start;
    if (cnt > 1600u) cnt = 1600u;
    if (tid < 32) hist[tid] = 0;
    __syncthreads();
    for (unsigned k = tid; k < cnt; k += 256) {
        float4 r = xb[start + k];
        stage[k] = r;
        atomicAdd(&hist[__float_as_uint(r.w) & 31u], 1u);
    }
    __syncthreads();
    if (tid < 64) {
        const unsigned c = (tid < 32) ? hist[tid] : 0u;
        unsigned v = c;
        for (int off = 1; off < 32; off <<= 1) {
            unsigned u = __shfl_up(v, off);
            if (tid >= off) v += u;
        }
        if (tid < 32) {
            const unsigned excl = v - c;
            const int node = p * 32 + tid;
            if (node < N) offsets[node] = start + excl;
            cur[tid] = start + excl;
            if (node == N - 1) offsets[N] = start + excl + c;
        }
    }
    __syncthreads();
    for (unsigned k = tid; k < cnt; k += 256) {
        float4 r = stage[k];
        const unsigned dst = atomicAdd(&cur[__float_as_uint(r.w) & 31u], 1u);
        xb[dst] = r;
    }
}

// ---------------------------------------------------------------------------
// K4: fused MLP1 + chunk-segmented max pool — EXACT measured-good version
// (92.6 µs, FETCH 17 MB / WRITE 18 MB, VALUBusy 58%). FROZEN.
// ---------------------------------------------------------------------------
__global__ __launch_bounds__(256, 3) void fused_mlp1_pool_kernel(
    const float4* __restrict__ xb, const unsigned* __restrict__ offsets,
    const float* __restrict__ pW1e, const float* __restrict__ pGB,
    const float* __restrict__ pSG, const unsigned short* __restrict__ pW2t,
    const float* __restrict__ b2,
    unsigned* __restrict__ segord, int P)
{
    __shared__ __align__(16) unsigned short shbt[64 * 260];  // 33.3 KB, [ch][row]
    __shared__ unsigned sn01[2];

    const int tid  = threadIdx.x;
    const int wv   = tid >> 6;
    const int lane = tid & 63;
    const int m    = lane & 15;
    const int quad = lane >> 4;
    const int base = blockIdx.x * 256;
    const int pos  = base + tid;
    const bool valid = (pos < P);

    // ---- W2 B-fragments + bias: straight from global into registers
    bf16x8 bfrag[4][2];
    float bc[4];
#pragma unroll
    for (int nt = 0; nt < 4; nt++) {
        bc[nt] = b2[nt * 16 + m];
#pragma unroll
        for (int s = 0; s < 2; s++)
            bfrag[nt][s] = *reinterpret_cast<const bf16x8*>(
                &pW2t[(nt * 16 + m) * 72 + s * 32 + quad * 8]);
    }

    // ---- own row load + LN stats via Gram trick
    float x0 = 0.f, x1 = 0.f, x2 = 0.f;
    if (valid) {
        float4 v = xb[pos];
        x0 = v.x; x1 = v.y; x2 = v.z;
        unsigned node = __float_as_uint(v.w);
        if (tid == 0) sn01[0] = node;
        if (tid == 255 || pos == P - 1) sn01[1] = node;
    }

    float rs, r2;
    {
        const float S0 = pSG[0], S1 = pSG[1], S2 = pSG[2], S3 = pSG[3];
        const float g00 = pSG[4], g01 = pSG[5], g02 = pSG[6], g03 = pSG[7];
        const float g11 = pSG[8], g12 = pSG[9], g13 = pSG[10];
        const float g22 = pSG[11], g23 = pSG[12], g33 = pSG[13];

        const float mu = fmaf(S0, x0, fmaf(S1, x1, fmaf(S2, x2, S3))) * (1.f / 64.f);
        float q = g33;
        q = fmaf(g00, x0 * x0, q);
        q = fmaf(g11, x1 * x1, q);
        q = fmaf(g22, x2 * x2, q);
        float c = fmaf(g01, x1, fmaf(g02, x2, g03));
        q = fmaf(2.f * x0, c, q);
        q = fmaf(2.f * x1, fmaf(g12, x2, g13), q);
        q = fmaf(2.f * x2, g23, q);
        float var = q * (1.f / 64.f) - mu * mu;
        var = var > 0.f ? var : 0.f;
        rs = rsqrtf(var + EPS_LN);
        r2 = -mu * rs;
    }

    // ---- deliver x/stats of the 4 rows this lane serves (wave-local rows)
    float xr0[4], xr1[4], xr2[4], rsr[4], r2r[4];
#pragma unroll
    for (int rt = 0; rt < 4; rt++) {
        const int src = rt * 16 + m;
        xr0[rt] = __shfl(x0, src);
        xr1[rt] = __shfl(x1, src);
        xr2[rt] = __shfl(x2, src);
        rsr[rt] = __shfl(rs, src);
        r2r[rt] = __shfl(r2, src);
    }

    // ---- Phase 1: layer-1 + LN + ReLU, computed directly in A-frag layout.
    u32x4 afr[4][2];
    {
        const float4* pw = (const float4*)pW1e;
        const float2* pg = (const float2*)pGB;
#pragma unroll
        for (int s = 0; s < 2; s++) {
#pragma unroll
            for (int up = 0; up < 4; up++) {
                const int ch = s * 32 + quad * 8 + up * 2;
                const float4 wA = pw[ch], wB = pw[ch + 1];
                const float2 gA = pg[ch], gB = pg[ch + 1];
#pragma unroll
                for (int rt = 0; rt < 4; rt++) {
                    float y0 = fmaf(xr0[rt], wA.x, fmaf(xr1[rt], wA.y,
                               fmaf(xr2[rt], wA.z, wA.w)));
                    float y1 = fmaf(xr0[rt], wB.x, fmaf(xr1[rt], wB.y,
                               fmaf(xr2[rt], wB.z, wB.w)));
                    float a0 = fmaf(fmaf(y0, rsr[rt], r2r[rt]), gA.x, gA.y);
                    float a1 = fmaf(fmaf(y1, rsr[rt], r2r[rt]), gB.x, gB.y);
                    a0 = a0 > 0.f ? a0 : 0.f;
                    a1 = a1 > 0.f ? a1 : 0.f;
                    afr[rt][s][up] = (unsigned)f2bf(a0) | ((unsigned)f2bf(a1) << 16);
                }
            }
        }
    }

    // ---- Phase 2: h = a @ W2 + b2 via MFMA; transposed ordkey16 store
#pragma unroll
    for (int rt = 0; rt < 4; rt++) {
        const int orow = wv * 64 + rt * 16 + quad * 4;   // C rows this lane owns
        const bf16x8 af0 = __builtin_bit_cast(bf16x8, afr[rt][0]);
        const bf16x8 af1 = __builtin_bit_cast(bf16x8, afr[rt][1]);
#pragma unroll
        for (int nt = 0; nt < 4; nt++) {
            f32x4 acc = {bc[nt], bc[nt], bc[nt], bc[nt]};
            acc = __builtin_amdgcn_mfma_f32_16x16x32_bf16(af0, bfrag[nt][0], acc, 0, 0, 0);
            acc = __builtin_amdgcn_mfma_f32_16x16x32_bf16(af1, bfrag[nt][1], acc, 0, 0, 0);
            const int col = nt * 16 + m;
            uint2 pk;
            pk.x = (unsigned)ok16(acc[0]) | ((unsigned)ok16(acc[1]) << 16);
            pk.y = (unsigned)ok16(acc[2]) | ((unsigned)ok16(acc[3]) << 16);
            *reinterpret_cast<uint2*>(&shbt[col * 260 + orow]) = pk;
        }
    }
    __syncthreads();

    // ---- Phase 3: segmented max, contiguous b64 reads + packed u16 max
    const int nValid = (P - base < 256) ? (P - base) : 256;
    if (nValid <= 0) return;
    const unsigned n0 = sn01[0];
    const unsigned n1 = sn01[1];
    const unsigned bEnd = (unsigned)(base + nValid);
    const int wave = tid >> 6;
    const int ch   = tid & 63;
    const unsigned short* rowp = &shbt[ch * 260];

    for (unsigned n = n0 + (unsigned)wave; n <= n1; n += 4) {
        const unsigned s = offsets[n];
        const unsigned e = offsets[n + 1];
        int lo = (int)(s > (unsigned)base ? s : (unsigned)base) - base;
        int hi = (int)(e < bEnd ? e : bEnd) - base;
        if (hi <= lo) continue;   // empty node inside range: leave 0
        u16x2 accv = {0, 0};
        unsigned short accs = 0;
        for (int r = lo & ~3; r < hi; r += 4) {
            uint2 d = *reinterpret_cast<const uint2*>(rowp + r);
            if (r >= lo && r + 4 <= hi) {
                u16x2 a = __builtin_bit_cast(u16x2, d.x);
                u16x2 b = __builtin_bit_cast(u16x2, d.y);
                accv = __builtin_elementwise_max(accv, __builtin_elementwise_max(a, b));
            } else {
                unsigned short v0 = (unsigned short)(d.x & 0xFFFFu);
                unsigned short v1 = (unsigned short)(d.x >> 16);
                unsigned short v2 = (unsigned short)(d.y & 0xFFFFu);
                unsigned short v3 = (unsigned short)(d.y >> 16);
                if (r     >= lo && r     < hi && v0 > accs) accs = v0;
                if (r + 1 >= lo && r + 1 < hi && v1 > accs) accs = v1;
                if (r + 2 >= lo && r + 2 < hi && v2 > accs) accs = v2;
                if (r + 3 >= lo && r + 3 < hi && v3 > accs) accs = v3;
            }
        }
        unsigned short k = accv.x > accv.y ? accv.x : accv.y;
        if (accs > k) k = accs;
        const unsigned key = ((unsigned)k) << 16;
        unsigned* dst = &segord[(size_t)n * 64 + ch];
        if (s >= (unsigned)base && e <= bEnd) *dst = key;   // sole writer
        else atomicMax(dst, key);                            // boundary node
    }
}

// ---------------------------------------------------------------------------
// K5: MLP2 fully in MFMA with split-bf16. Grid 512 (measured better than
// 2048 in R5 A/B: +13 µs at 2048).
// ---------------------------------------------------------------------------
__global__ __launch_bounds__(256) void mlp2_mfma_kernel(
    const unsigned* __restrict__ segord,
    const unsigned short* __restrict__ W3th, const unsigned short* __restrict__ W3tl,
    const unsigned short* __restrict__ W4th, const unsigned short* __restrict__ W4tl,
    const float* __restrict__ b3, const float* __restrict__ g2,
    const float* __restrict__ be2, const float* __restrict__ b4,
    float* __restrict__ out, int N)
{
    __shared__ __align__(16) unsigned short sa2[32 * 72];
    __shared__ __align__(16) float st[32 * 132];
    __shared__ __align__(16) unsigned short suh[32 * 136];
    __shared__ __align__(16) unsigned short sul[32 * 136];
    __shared__ float2 sred[32][8];
    __shared__ float sg2[128], sbe2[128];

    const int tid  = threadIdx.x;
    const int wv   = tid >> 6;
    const int lane = tid & 63;
    const int m    = lane & 15;
    const int quad = lane >> 4;

    if (tid < 128) { sg2[tid] = g2[tid]; sbe2[tid] = be2[tid]; }

    bf16x8 fw3h[2][2], fw3l[2][2];
    bf16x8 fw4h[2][4], fw4l[2][4];
    float bias3[2], bias4[2];
#pragma unroll
    for (int nti = 0; nti < 2; nti++) {
        const int nrow = (wv * 2 + nti) * 16 + m;
        bias3[nti] = b3[nrow];
        bias4[nti] = b4[nrow];
#pragma unroll
        for (int ks = 0; ks < 2; ks++) {
            fw3h[nti][ks] = *reinterpret_cast<const bf16x8*>(&W3th[nrow * 64 + ks * 32 + quad * 8]);
            fw3l[nti][ks] = *reinterpret_cast<const bf16x8*>(&W3tl[nrow * 64 + ks * 32 + quad * 8]);
        }
#pragma unroll
        for (int ks = 0; ks < 4; ks++) {
            fw4h[nti][ks] = *reinterpret_cast<const bf16x8*>(&W4th[nrow * 128 + ks * 32 + quad * 8]);
            fw4l[nti][ks] = *reinterpret_cast<const bf16x8*>(&W4tl[nrow * 128 + ks * 32 + quad * 8]);
        }
    }
    __syncthreads();

    for (int nb = blockIdx.x * 32; nb < N; nb += gridDim.x * 32) {
        {
            const int node = tid >> 3;
            const int k8   = (tid & 7) * 8;
            const uint4* sp = (const uint4*)&segord[(size_t)(nb + node) * 64 + k8];
            uint4 q0 = sp[0], q1 = sp[1];
            bf16x8 v;
            v[0] = (short)f2bf(decseg(q0.x));
            v[1] = (short)f2bf(decseg(q0.y));
            v[2] = (short)f2bf(decseg(q0.z));
            v[3] = (short)f2bf(decseg(q0.w));
            v[4] = (short)f2bf(decseg(q1.x));
            v[5] = (short)f2bf(decseg(q1.y));
            v[6] = (short)f2bf(decseg(q1.z));
            v[7] = (short)f2bf(decseg(q1.w));
            *reinterpret_cast<bf16x8*>(&sa2[node * 72 + k8]) = v;
        }
        __syncthreads();

#pragma unroll
        for (int mt = 0; mt < 2; mt++) {
            bf16x8 a0 = *reinterpret_cast<const bf16x8*>(&sa2[(mt * 16 + m) * 72 + quad * 8]);
            bf16x8 a1 = *reinterpret_cast<const bf16x8*>(&sa2[(mt * 16 + m) * 72 + 32 + quad * 8]);
#pragma unroll
            for (int nti = 0; nti < 2; nti++) {
                f32x4 acc = {bias3[nti], bias3[nti], bias3[nti], bias3[nti]};
                acc = __builtin_amdgcn_mfma_f32_16x16x32_bf16(a0, fw3h[nti][0], acc, 0, 0, 0);
                acc = __builtin_amdgcn_mfma_f32_16x16x32_bf16(a1, fw3h[nti][1], acc, 0, 0, 0);
                acc = __builtin_amdgcn_mfma_f32_16x16x32_bf16(a0, fw3l[nti][0], acc, 0, 0, 0);
                acc = __builtin_amdgcn_mfma_f32_16x16x32_bf16(a1, fw3l[nti][1], acc, 0, 0, 0);
#pragma unroll
                for (int r = 0; r < 4; r++)
                    st[(mt * 16 + quad * 4 + r) * 132 + (wv * 2 + nti) * 16 + m] = acc[r];
            }
        }
        __syncthreads();

        {
            const int node = tid >> 3;
            const int seg  = tid & 7;
            const float4* rp = (const float4*)&st[node * 132 + seg * 16];
            float4 v0 = rp[0], v1 = rp[1], v2 = rp[2], v3 = rp[3];
            float s1 = v0.x + v0.y + v0.z + v0.w + v1.x + v1.y + v1.z + v1.w
                     + v2.x + v2.y + v2.z + v2.w + v3.x + v3.y + v3.z + v3.w;
            float s2 = 0.f;
            s2 = fmaf(v0.x, v0.x, s2); s2 = fmaf(v0.y, v0.y, s2); s2 = fmaf(v0.z, v0.z, s2); s2 = fmaf(v0.w, v0.w, s2);
            s2 = fmaf(v1.x, v1.x, s2); s2 = fmaf(v1.y, v1.y, s2); s2 = fmaf(v1.z, v1.z, s2); s2 = fmaf(v1.w, v1.w, s2);
            s2 = fmaf(v2.x, v2.x, s2); s2 = fmaf(v2.y, v2.y, s2); s2 = fmaf(v2.z, v2.z, s2); s2 = fmaf(v2.w, v2.w, s2);
            s2 = fmaf(v3.x, v3.x, s2); s2 = fmaf(v3.y, v3.y, s2); s2 = fmaf(v3.z, v3.z, s2); s2 = fmaf(v3.w, v3.w, s2);
            sred[node][seg] = make_float2(s1, s2);
            __syncthreads();

            float t1 = 0.f, t2 = 0.f;
#pragma unroll
            for (int i = 0; i < 8; i++) { float2 r = sred[node][i]; t1 += r.x; t2 += r.y; }
            const float mu  = t1 * (1.f / 128.f);
            float var = t2 * (1.f / 128.f) - mu * mu;
            var = var > 0.f ? var : 0.f;
            const float rsd = rsqrtf(var + EPS_LN);

            float tv[16] = {v0.x, v0.y, v0.z, v0.w, v1.x, v1.y, v1.z, v1.w,
                            v2.x, v2.y, v2.z, v2.w, v3.x, v3.y, v3.z, v3.w};
            bf16x8 vh[2], vl[2];
#pragma unroll
            for (int i = 0; i < 16; i++) {
                const int j = seg * 16 + i;
                float u = fmaf((tv[i] - mu) * rsd, sg2[j], sbe2[j]);
                u = u > 0.f ? u : 0.f;
                unsigned short uh = f2bf(u);
                unsigned short ul = f2bf(u - bf2f(uh));
                vh[i >> 3][i & 7] = (short)uh;
                vl[i >> 3][i & 7] = (short)ul;
            }
            *reinterpret_cast<bf16x8*>(&suh[node * 136 + seg * 16])     = vh[0];
            *reinterpret_cast<bf16x8*>(&suh[node * 136 + seg * 16 + 8]) = vh[1];
            *reinterpret_cast<bf16x8*>(&sul[node * 136 + seg * 16])     = vl[0];
            *reinterpret_cast<bf16x8*>(&sul[node * 136 + seg * 16 + 8]) = vl[1];
        }
        __syncthreads();

#pragma unroll
        for (int mt = 0; mt < 2; mt++) {
            bf16x8 ah[4], al[4];
#pragma unroll
            for (int ks = 0; ks < 4; ks++) {
                ah[ks] = *reinterpret_cast<const bf16x8*>(&suh[(mt * 16 + m) * 136 + ks * 32 + quad * 8]);
                al[ks] = *reinterpret_cast<const bf16x8*>(&sul[(mt * 16 + m) * 136 + ks * 32 + quad * 8]);
            }
#pragma unroll
            for (int nti = 0; nti < 2; nti++) {
                f32x4 acc = {bias4[nti], bias4[nti], bias4[nti], bias4[nti]};
#pragma unroll
                for (int ks = 0; ks < 4; ks++) {
                    acc = __builtin_amdgcn_mfma_f32_16x16x32_bf16(ah[ks], fw4h[nti][ks], acc, 0, 0, 0);
                    acc = __builtin_amdgcn_mfma_f32_16x16x32_bf16(al[ks], fw4h[nti][ks], acc, 0, 0, 0);
                    acc = __builtin_amdgcn_mfma_f32_16x16x32_bf16(ah[ks], fw4l[nti][ks], acc, 0, 0, 0);
                }
#pragma unroll
                for (int r = 0; r < 4; r++) {
                    const int node = nb + mt * 16 + quad * 4 + r;
                    if (node < N)
                        out[(size_t)node * 128 + (wv * 2 + nti) * 16 + m] = acc[r];
                }
            }
        }
        __syncthreads();
    }
}

extern "C" void kernel_launch(void* const* d_in, const int* in_sizes, int n_in,
                              void* d_out, int out_size, void* d_ws, size_t ws_size,
                              hipStream_t stream) {
    const float* x    = (const float*)d_in[0];
    const int*   bidx = (const int*)d_in[1];
    const float* W1  = (const float*)d_in[3];
    const float* b1  = (const float*)d_in[4];
    const float* g1  = (const float*)d_in[5];
    const float* be1 = (const float*)d_in[6];
    const float* W2  = (const float*)d_in[7];
    const float* b2  = (const float*)d_in[8];
    const float* W3  = (const float*)d_in[9];
    const float* b3  = (const float*)d_in[10];
    const float* g2  = (const float*)d_in[11];
    const float* be2 = (const float*)d_in[12];
    const float* W4  = (const float*)d_in[13];
    const float* b4  = (const float*)d_in[14];

    const int P = in_sizes[0] / 3;
    const int N = out_size / 128;
    const int nparts = (N + 31) >> 5;            // <= 2048
    const int nblk   = (P + 16383) / 16384;      // <= 128 (16384 pts/block)

    uintptr_t w = (uintptr_t)d_ws;
    auto align = [](uintptr_t v) { return (v + 255) & ~(uintptr_t)255; };
    unsigned* blockHist = (unsigned*)align(w);     w = (uintptr_t)(blockHist + (size_t)nblk * 2048);
    unsigned* binTotal  = (unsigned*)align(w);     w = (uintptr_t)(binTotal  + 2048);
    unsigned* partBase  = (unsigned*)align(w);     w = (uintptr_t)(partBase  + 2049);
    unsigned* offsets   = (unsigned*)align(w);     w = (uintptr_t)(offsets   + N + 1);
    float4*   xb        = (float4*)align(w);       w = (uintptr_t)(xb        + P);
    unsigned* segord    = (unsigned*)align(w);     w = (uintptr_t)(segord    + (size_t)N * 64);
    float*    pW1e      = (float*)align(w);        w = (uintptr_t)(pW1e      + 256);
    float*    pGB       = (float*)align(w);        w = (uintptr_t)(pGB       + 128);
    float*    pSG       = (float*)align(w);        w = (uintptr_t)(pSG       + 16);
    unsigned short* pW2t = (unsigned short*)align(w); w = (uintptr_t)(pW2t + 64 * 72);
    unsigned short* W3th = (unsigned short*)align(w); w = (uintptr_t)(W3th + 128 * 64);
    unsigned short* W3tl = (unsigned short*)align(w); w = (uintptr_t)(W3tl + 128 * 64);
    unsigned short* W4th = (unsigned short*)align(w); w = (uintptr_t)(W4th + 128 * 128);
    unsigned short* W4tl = (unsigned short*)align(w); w = (uintptr_t)(W4tl + 128 * 128);

    const int segWords = N * 64;

    s1_fused<<<nblk + 1, 256, 0, stream>>>(
        bidx, blockHist, P, nblk, segord, segWords,
        W1, b1, g1, be1, W2, W3, W4,
        pW1e, pGB, pSG, pW2t, W3th, W3tl, W4th, W4tl);

    s2ac_scan<<<nparts, 256, 0, stream>>>(blockHist, binTotal, nblk);
    s2b_scan<<<1, 1024, 0, stream>>>(binTotal, partBase, nparts, P);
    s3_scatter<<<nblk, 256, 0, stream>>>(bidx, x, blockHist, partBase, xb, P);
    s4_csr<<<nparts, 256, 0, stream>>>(partBase, offsets, xb, N);

    fused_mlp1_pool_kernel<<<(P + 255) / 256, 256, 0, stream>>>(
        xb, offsets, pW1e, pGB, pSG, pW2t, b2, segord, P);

    mlp2_mfma_kernel<<<512, 256, 0, stream>>>(
        segord, W3th, W3tl, W4th, W4tl, b3, g2, be2, b4, (float*)d_out, N);
}